// Round 1
// baseline (7411.362 us; speedup 1.0000x reference)
//
#include <hip/hip_runtime.h>
#include <math.h>

#define N_NODES_C  25000
#define N_EDGES_C  100000
#define N_GRAPHS_C 1000
// DIM = 64, NUM_FEAT = 14, EDGE_FEAT = 4, HIDDEN_EDGE = 128

__device__ __forceinline__ float lrelu(float x) { return x > 0.f ? x : 0.01f * x; }
__device__ __forceinline__ float sigm(float x)  { return 1.f / (1.f + __expf(-x)); }

// ---------------------------------------------------------------- lin0
__global__ void lin0_kernel(const float* __restrict__ x,
                            const float* __restrict__ w, const float* __restrict__ b,
                            float* __restrict__ out, float* __restrict__ h) {
  int n = blockIdx.x, o = threadIdx.x;
  __shared__ float xr[14];
  if (o < 14) xr[o] = x[n * 14 + o];
  __syncthreads();
  float s = b[o];
#pragma unroll
  for (int j = 0; j < 14; ++j) s += xr[j] * w[o * 14 + j];
  s = lrelu(s);
  out[n * 64 + o] = s;
  h[n * 64 + o] = s;
}

// ---------------------------------------------------------------- degree
__global__ void deg_kernel(const int* __restrict__ ei, float* __restrict__ deg) {
  int e = blockIdx.x * blockDim.x + threadIdx.x;
  if (e < N_EDGES_C) atomicAdd(&deg[ei[N_EDGES_C + e]], 1.f);
}

__global__ void invdeg_kernel(float* __restrict__ deg) {
  int n = blockIdx.x * blockDim.x + threadIdx.x;
  if (n < N_NODES_C) { float v = deg[n]; deg[n] = v > 0.f ? 1.f / v : 0.f; }
}

// graph offsets via binary search over sorted batch
__global__ void goff_kernel(const int* __restrict__ batch, int* __restrict__ goff) {
  int g = blockIdx.x * blockDim.x + threadIdx.x;
  if (g > N_GRAPHS_C) return;
  int lo = 0, hi = N_NODES_C;
  while (lo < hi) { int mid = (lo + hi) >> 1; if (batch[mid] < g) lo = mid + 1; else hi = mid; }
  goff[g] = lo;
}

// ---------------------------------------------------------------- NNConv message + scatter
// msg_e[o] = sum_d x[src_e][d] * ( sum_h A[e,h]*W2[(d*64+o)*128+h] + b2[d*64+o] )
// Block: 64 edges x 64 outputs, 256 threads (thread tile 4e x 4o), LDS = 80 KB -> 2 blocks/CU.
__global__ __launch_bounds__(256, 2) void msg_kernel(
    const float* __restrict__ nodef,     // [N,64] current node features
    const int*   __restrict__ ei,        // [2,E]
    const float* __restrict__ eattr,     // [E,4]
    const float* __restrict__ net_w1,    // [128,4]
    const float* __restrict__ net_b1,    // [128]
    const float* __restrict__ net_w2,    // [4096,128]
    const float* __restrict__ net_b2,    // [4096]
    float* __restrict__ aggr)            // [N,64]
{
  __shared__ float4 As[64 * 32];   // A[e][h4] at slot e*32 + (h4 ^ (e&7))  (32 KB)
  __shared__ float4 Wst[64 * 32];  // W2 slab [o][h4] at slot o*32 + (h4 ^ (o&7)) (32 KB)
  __shared__ float  xs[64 * 64];   // x[e][d] (16 KB)

  const int tid = threadIdx.x;
  const int e0 = blockIdx.x * 64;

  // ---- Stage A: edge-MLP hidden, 64 edges x 128 hidden
  {
    const int hh = tid & 127;
    const float w0 = net_w1[hh * 4 + 0], w1 = net_w1[hh * 4 + 1];
    const float w2v = net_w1[hh * 4 + 2], w3 = net_w1[hh * 4 + 3];
    const float bb = net_b1[hh];
    const int ebase = tid >> 7;  // 0 or 1
#pragma unroll
    for (int t = 0; t < 32; ++t) {
      int e = ebase + t * 2;
      int ge = e0 + e;
      float a = 0.f;
      if (ge < N_EDGES_C) {
        const float4 at = *(const float4*)(eattr + ge * 4);
        a = bb + at.x * w0 + at.y * w1 + at.z * w2v + at.w * w3;
        a = lrelu(a);
      }
      int slot = e * 32 + ((hh >> 2) ^ (e & 7));
      ((float*)As)[slot * 4 + (hh & 3)] = a;
    }
  }
  // ---- Stage x: gather source rows
  {
#pragma unroll
    for (int t = 0; t < 16; ++t) {
      int flat = tid + t * 256;       // < 4096
      int e = flat >> 6, d = flat & 63;
      int ge = e0 + e;
      xs[e * 64 + d] = (ge < N_EDGES_C) ? nodef[ei[ge] * 64 + d] : 0.f;
    }
  }

  const int eg = tid & 15, og = tid >> 4;
  const int e_l0 = eg, e_l1 = eg + 16, e_l2 = eg + 32, e_l3 = eg + 48;
  const int o_l0 = og, o_l1 = og + 16, o_l2 = og + 32, o_l3 = og + 48;
  const int ex = eg & 7, ox = og & 7;  // same for all 4 rows (stride 16)

  float acc[4][4];
#pragma unroll
  for (int i = 0; i < 4; ++i)
#pragma unroll
    for (int j = 0; j < 4; ++j) acc[i][j] = 0.f;

  for (int d = 0; d < 64; ++d) {
    __syncthreads();  // also covers stage A/x on first iteration
    // stream one 32 KB W2 slab (contiguous: (d*64+o)*128+h = d*8192 + o*128 + h)
    const float4* src4 = (const float4*)(net_w2 + d * 8192);
#pragma unroll
    for (int t = 0; t < 8; ++t) {
      int f4 = tid + t * 256;       // < 2048
      int o = f4 >> 5, h4 = f4 & 31;
      Wst[o * 32 + (h4 ^ (o & 7))] = src4[f4];
    }
    __syncthreads();

    float accP[4][4];
#pragma unroll
    for (int i = 0; i < 4; ++i)
#pragma unroll
      for (int j = 0; j < 4; ++j) accP[i][j] = 0.f;

#pragma unroll 8
    for (int h4 = 0; h4 < 32; ++h4) {
      const int ax = h4 ^ ex, bx = h4 ^ ox;
      float4 a0 = As[e_l0 * 32 + ax];
      float4 a1 = As[e_l1 * 32 + ax];
      float4 a2 = As[e_l2 * 32 + ax];
      float4 a3 = As[e_l3 * 32 + ax];
      float4 b0 = Wst[o_l0 * 32 + bx];
      float4 b1 = Wst[o_l1 * 32 + bx];
      float4 b2v = Wst[o_l2 * 32 + bx];
      float4 b3 = Wst[o_l3 * 32 + bx];
#define DOT4(P, A, B) P += A.x*B.x; P += A.y*B.y; P += A.z*B.z; P += A.w*B.w;
      DOT4(accP[0][0], a0, b0) DOT4(accP[0][1], a0, b1) DOT4(accP[0][2], a0, b2v) DOT4(accP[0][3], a0, b3)
      DOT4(accP[1][0], a1, b0) DOT4(accP[1][1], a1, b1) DOT4(accP[1][2], a1, b2v) DOT4(accP[1][3], a1, b3)
      DOT4(accP[2][0], a2, b0) DOT4(accP[2][1], a2, b1) DOT4(accP[2][2], a2, b2v) DOT4(accP[2][3], a2, b3)
      DOT4(accP[3][0], a3, b0) DOT4(accP[3][1], a3, b1) DOT4(accP[3][2], a3, b2v) DOT4(accP[3][3], a3, b3)
#undef DOT4
    }

    const float bias0 = net_b2[d * 64 + o_l0];
    const float bias1 = net_b2[d * 64 + o_l1];
    const float bias2 = net_b2[d * 64 + o_l2];
    const float bias3 = net_b2[d * 64 + o_l3];
    const float x0 = xs[e_l0 * 64 + d];
    const float x1 = xs[e_l1 * 64 + d];
    const float x2 = xs[e_l2 * 64 + d];
    const float x3 = xs[e_l3 * 64 + d];
    acc[0][0] += x0 * (accP[0][0] + bias0); acc[0][1] += x0 * (accP[0][1] + bias1);
    acc[0][2] += x0 * (accP[0][2] + bias2); acc[0][3] += x0 * (accP[0][3] + bias3);
    acc[1][0] += x1 * (accP[1][0] + bias0); acc[1][1] += x1 * (accP[1][1] + bias1);
    acc[1][2] += x1 * (accP[1][2] + bias2); acc[1][3] += x1 * (accP[1][3] + bias3);
    acc[2][0] += x2 * (accP[2][0] + bias0); acc[2][1] += x2 * (accP[2][1] + bias1);
    acc[2][2] += x2 * (accP[2][2] + bias2); acc[2][3] += x2 * (accP[2][3] + bias3);
    acc[3][0] += x3 * (accP[3][0] + bias0); acc[3][1] += x3 * (accP[3][1] + bias1);
    acc[3][2] += x3 * (accP[3][2] + bias2); acc[3][3] += x3 * (accP[3][3] + bias3);
  }

  // scatter-add into aggr[dst]
  const int el[4] = {e_l0, e_l1, e_l2, e_l3};
  const int ol[4] = {o_l0, o_l1, o_l2, o_l3};
#pragma unroll
  for (int i = 0; i < 4; ++i) {
    int ge = e0 + el[i];
    if (ge < N_EDGES_C) {
      int dn = ei[N_EDGES_C + ge];
#pragma unroll
      for (int j = 0; j < 4; ++j) atomicAdd(&aggr[dn * 64 + ol[j]], acc[i][j]);
    }
  }
}

// ---------------------------------------------------------------- root matmul + GRU
__global__ void node_update_kernel(
    const float* __restrict__ aggr, const float* __restrict__ invdeg,
    const float* __restrict__ conv_root, const float* __restrict__ conv_bias,
    const float* __restrict__ w_ih, const float* __restrict__ w_hh,
    const float* __restrict__ b_ih, const float* __restrict__ b_hh,
    float* __restrict__ h, float* __restrict__ out) {
  int n = blockIdx.x, o = threadIdx.x;
  __shared__ float outr[64], hr[64], mr[64];
  float hv = h[n * 64 + o];
  outr[o] = out[n * 64 + o];
  hr[o] = hv;
  __syncthreads();
  float root = 0.f;
#pragma unroll
  for (int d = 0; d < 64; ++d) root += outr[d] * conv_root[d * 64 + o];
  float m = lrelu(aggr[n * 64 + o] * invdeg[n] + root + conv_bias[o]);
  mr[o] = m;
  __syncthreads();
  float gi_r = b_ih[o], gi_z = b_ih[64 + o], gi_n = b_ih[128 + o];
  float gh_r = b_hh[o], gh_z = b_hh[64 + o], gh_n = b_hh[128 + o];
#pragma unroll 16
  for (int d = 0; d < 64; ++d) {
    float mv = mr[d], hvd = hr[d];
    gi_r += mv * w_ih[o * 64 + d];
    gi_z += mv * w_ih[(64 + o) * 64 + d];
    gi_n += mv * w_ih[(128 + o) * 64 + d];
    gh_r += hvd * w_hh[o * 64 + d];
    gh_z += hvd * w_hh[(64 + o) * 64 + d];
    gh_n += hvd * w_hh[(128 + o) * 64 + d];
  }
  float r = sigm(gi_r + gh_r), z = sigm(gi_z + gh_z);
  float nn = tanhf(gi_n + r * gh_n);
  float hn = (1.f - z) * nn + z * hv;
  h[n * 64 + o] = hn;
  out[n * 64 + o] = hn;
}

// ---------------------------------------------------------------- Set2Set LSTM cell
__global__ void lstm_kernel(const float* __restrict__ qstar,
    const float* __restrict__ w_ih, const float* __restrict__ w_hh,
    const float* __restrict__ b_ih, const float* __restrict__ b_hh,
    float* __restrict__ hl, float* __restrict__ cl) {
  int g = blockIdx.x, o = threadIdx.x;
  __shared__ float qs[128], hs[64];
  qs[o] = qstar[g * 128 + o];
  qs[64 + o] = qstar[g * 128 + 64 + o];
  float hv = hl[g * 64 + o];
  hs[o] = hv;
  __syncthreads();
  float gv[4];
#pragma unroll
  for (int k = 0; k < 4; ++k) {
    float s = b_ih[k * 64 + o] + b_hh[k * 64 + o];
    const float* wi = w_ih + (k * 64 + o) * 128;
    const float* wh = w_hh + (k * 64 + o) * 64;
#pragma unroll 16
    for (int j = 0; j < 128; ++j) s += qs[j] * wi[j];
#pragma unroll 16
    for (int j = 0; j < 64; ++j) s += hs[j] * wh[j];
    gv[k] = s;
  }
  float iv = sigm(gv[0]), fv = sigm(gv[1]), gg = tanhf(gv[2]), ov = sigm(gv[3]);
  float c = fv * cl[g * 64 + o] + iv * gg;
  float hn = ov * tanhf(c);
  cl[g * 64 + o] = c;
  hl[g * 64 + o] = hn;
}

// ---------------------------------------------------------------- segment softmax + readout
__global__ void attn_kernel(const float* __restrict__ out, const float* __restrict__ hl,
    const int* __restrict__ goff, float* __restrict__ ebuf, float* __restrict__ qstar) {
  int g = blockIdx.x, t = threadIdx.x;
  float qv = hl[g * 64 + t];
  int s0 = goff[g], s1 = goff[g + 1];
  float emax = -3.0e38f;
  for (int n = s0; n < s1; ++n) {
    float p = out[n * 64 + t] * qv;
#pragma unroll
    for (int off = 32; off > 0; off >>= 1) p += __shfl_down(p, off);
    float en = __shfl(p, 0);
    if (t == 0) ebuf[n] = en;
    emax = fmaxf(emax, en);
  }
  __syncthreads();  // drain ebuf writes (vmcnt) before cross-lane reads
  float lsum = 0.f;
  for (int n = s0 + t; n < s1; n += 64) {
    float ex = __expf(ebuf[n] - emax);
    ebuf[n] = ex;
    lsum += ex;
  }
#pragma unroll
  for (int off = 32; off > 0; off >>= 1) lsum += __shfl_down(lsum, off);
  float denom = __shfl(lsum, 0);
  __syncthreads();
  float r = 0.f;
  for (int n = s0; n < s1; ++n) r += ebuf[n] * out[n * 64 + t];
  if (s1 > s0) r /= denom;
  qstar[g * 128 + t] = qv;
  qstar[g * 128 + 64 + t] = r;
}

// ---------------------------------------------------------------- final linear
__global__ void final_kernel(const float* __restrict__ qstar, const float* __restrict__ lw,
                             const float* __restrict__ lb, float* __restrict__ dout) {
  int b = blockIdx.x * blockDim.x + threadIdx.x;
  if (b >= N_GRAPHS_C) return;
  float s = lb[0];
#pragma unroll 16
  for (int j = 0; j < 128; ++j) s += qstar[b * 128 + j] * lw[j];
  dout[b] = s;
}

// ---------------------------------------------------------------- launch
extern "C" void kernel_launch(void* const* d_in, const int* in_sizes, int n_in,
                              void* d_out, int out_size, void* d_ws, size_t ws_size,
                              hipStream_t stream) {
  const float* x         = (const float*)d_in[0];
  const int*   ei        = (const int*)  d_in[1];
  const float* eattr     = (const float*)d_in[2];
  const int*   batch     = (const int*)  d_in[3];
  const float* lin0_w    = (const float*)d_in[4];
  const float* lin0_b    = (const float*)d_in[5];
  const float* net_w1    = (const float*)d_in[6];
  const float* net_b1    = (const float*)d_in[7];
  const float* net_w2    = (const float*)d_in[8];
  const float* net_b2    = (const float*)d_in[9];
  const float* conv_root = (const float*)d_in[10];
  const float* conv_bias = (const float*)d_in[11];
  const float* gru_w_ih  = (const float*)d_in[12];
  const float* gru_w_hh  = (const float*)d_in[13];
  const float* gru_b_ih  = (const float*)d_in[14];
  const float* gru_b_hh  = (const float*)d_in[15];
  const float* lstm_w_ih = (const float*)d_in[16];
  const float* lstm_w_hh = (const float*)d_in[17];
  const float* lstm_b_ih = (const float*)d_in[18];
  const float* lstm_b_hh = (const float*)d_in[19];
  const float* lin_w     = (const float*)d_in[20];
  const float* lin_b     = (const float*)d_in[21];

  // workspace layout (floats) — total ~19.5 MB
  float* ws    = (float*)d_ws;
  float* out   = ws;                  // 1,600,000
  float* h     = out + 1600000;       // 1,600,000
  float* aggr  = h + 1600000;         // 1,600,000
  float* deg   = aggr + 1600000;      // 25,000 (becomes inv_deg in place)
  float* ebuf  = deg + 25000;         // 25,000
  float* hl    = ebuf + 25000;        // 64,000
  float* cl    = hl + 64000;          // 64,000
  float* qstar = cl + 64000;          // 128,000
  int*   goff  = (int*)(qstar + 128000); // 1,001

  hipMemsetAsync(deg, 0, 25000 * sizeof(float), stream);
  hipMemsetAsync(hl, 0, (64000 + 64000 + 128000) * sizeof(float), stream);  // hl, cl, qstar

  lin0_kernel<<<N_NODES_C, 64, 0, stream>>>(x, lin0_w, lin0_b, out, h);
  deg_kernel<<<(N_EDGES_C + 255) / 256, 256, 0, stream>>>(ei, deg);
  invdeg_kernel<<<(N_NODES_C + 255) / 256, 256, 0, stream>>>(deg);
  goff_kernel<<<(N_GRAPHS_C + 256) / 256, 256, 0, stream>>>(batch, goff);

  for (int step = 0; step < 3; ++step) {
    hipMemsetAsync(aggr, 0, 1600000 * sizeof(float), stream);
    msg_kernel<<<(N_EDGES_C + 63) / 64, 256, 0, stream>>>(
        out, ei, eattr, net_w1, net_b1, net_w2, net_b2, aggr);
    node_update_kernel<<<N_NODES_C, 64, 0, stream>>>(
        aggr, deg, conv_root, conv_bias, gru_w_ih, gru_w_hh, gru_b_ih, gru_b_hh, h, out);
  }

  for (int s = 0; s < 3; ++s) {
    lstm_kernel<<<N_GRAPHS_C, 64, 0, stream>>>(qstar, lstm_w_ih, lstm_w_hh, lstm_b_ih, lstm_b_hh, hl, cl);
    attn_kernel<<<N_GRAPHS_C, 64, 0, stream>>>(out, hl, goff, ebuf, qstar);
  }

  final_kernel<<<(N_GRAPHS_C + 127) / 128, 128, 0, stream>>>(qstar, lin_w, lin_b, (float*)d_out);
}

// Round 2
// 1813.644 us; speedup vs baseline: 4.0864x; 4.0864x over previous
//
#include <hip/hip_runtime.h>
#include <math.h>

#define N_NODES_C  25000
#define N_EDGES_C  100000
#define N_GRAPHS_C 1000
#define EPB 128  // edges per block in msg_kernel

typedef __attribute__((ext_vector_type(8))) short   bf16x8;
typedef __attribute__((ext_vector_type(4))) unsigned short us4;
typedef __attribute__((ext_vector_type(4))) float   f32x4;

__device__ __forceinline__ float lrelu(float x) { return x > 0.f ? x : 0.01f * x; }
__device__ __forceinline__ float sigm(float x)  { return 1.f / (1.f + __expf(-x)); }
__device__ __forceinline__ unsigned short f2bf(float f) {
  union { float f; unsigned int u; } v; v.f = f;
  unsigned int r = v.u + 0x7fffu + ((v.u >> 16) & 1u);  // RNE
  return (unsigned short)(r >> 16);
}

// ---------------------------------------------------------------- lin0
__global__ void lin0_kernel(const float* __restrict__ x,
                            const float* __restrict__ w, const float* __restrict__ b,
                            float* __restrict__ out, float* __restrict__ h) {
  int n = blockIdx.x, o = threadIdx.x;
  __shared__ float xr[14];
  if (o < 14) xr[o] = x[n * 14 + o];
  __syncthreads();
  float s = b[o];
#pragma unroll
  for (int j = 0; j < 14; ++j) s += xr[j] * w[o * 14 + j];
  s = lrelu(s);
  out[n * 64 + o] = s;
  h[n * 64 + o] = s;
}

// ---------------------------------------------------------------- degree
__global__ void deg_kernel(const int* __restrict__ ei, float* __restrict__ deg) {
  int e = blockIdx.x * blockDim.x + threadIdx.x;
  if (e < N_EDGES_C) atomicAdd(&deg[ei[N_EDGES_C + e]], 1.f);
}

__global__ void invdeg_kernel(float* __restrict__ deg) {
  int n = blockIdx.x * blockDim.x + threadIdx.x;
  if (n < N_NODES_C) { float v = deg[n]; deg[n] = v > 0.f ? 1.f / v : 0.f; }
}

// graph offsets via binary search over sorted batch
__global__ void goff_kernel(const int* __restrict__ batch, int* __restrict__ goff) {
  int g = blockIdx.x * blockDim.x + threadIdx.x;
  if (g > N_GRAPHS_C) return;
  int lo = 0, hi = N_NODES_C;
  while (lo < hi) { int mid = (lo + hi) >> 1; if (batch[mid] < g) lo = mid + 1; else hi = mid; }
  goff[g] = lo;
}

// ---------------------------------------------------------------- NNConv message + scatter (MFMA)
// Per d-slab: P[e,o] = b2[d*64+o] + sum_h A_bf16[e,h] * W2_bf16[d*64+o, h]  (MFMA, fp32 acc)
//             acc[e,o] += x[e,d] * P[e,o]                                   (fp32)
// Block: 128 edges, 4 waves; wave tile 64e x 32o. LDS exactly 80 KB -> 2 blocks/CU.
__global__ __launch_bounds__(256, 2) void msg_kernel(
    const float* __restrict__ nodef,     // [N,64]
    const int*   __restrict__ ei,        // [2,E]
    const float* __restrict__ eattr,     // [E,4]
    const float* __restrict__ net_w1,    // [128,4]
    const float* __restrict__ net_b1,    // [128]
    const float* __restrict__ net_w2,    // [4096,128]
    const float* __restrict__ net_b2,    // [4096]
    float* __restrict__ aggr)            // [N,64]
{
  __shared__ unsigned short As[EPB * 128];  // 32 KB  A[e][h], h ^= (e&7)<<3
  __shared__ unsigned short Ws[64 * 128];   // 16 KB  W2slab[o][h], h ^= (o&7)<<3
  __shared__ float          xs[64 * EPB];   // 32 KB  xs[d][e] (no swizzle needed)

  const int tid = threadIdx.x;
  const int e0 = blockIdx.x * EPB;

  // ---- Stage A: edge-MLP hidden, 128 edges x 128 h (bf16, swizzled)
  {
    const int hh = tid & 127;
    const float w0 = net_w1[hh * 4 + 0], w1v = net_w1[hh * 4 + 1];
    const float w2v = net_w1[hh * 4 + 2], w3v = net_w1[hh * 4 + 3];
    const float bb = net_b1[hh];
    const int ebase = tid >> 7;  // 0 or 1
    const int hsw_base = hh;     // swizzle applied per-row below
#pragma unroll 4
    for (int t = 0; t < 64; ++t) {
      int e = ebase + t * 2;
      int ge = e0 + e;
      float a = 0.f;
      if (ge < N_EDGES_C) {
        const float4 at = *(const float4*)(eattr + (size_t)ge * 4);
        a = bb + at.x * w0 + at.y * w1v + at.z * w2v + at.w * w3v;
        a = lrelu(a);
      }
      As[e * 128 + (hsw_base ^ ((e & 7) << 3))] = f2bf(a);
    }
  }
  // ---- Stage x (transposed): xs[d][e] = nodef[src_e][d]
  {
    const int e = tid >> 1, dh = (tid & 1) * 32;
    int ge = e0 + e;
    if (ge < N_EDGES_C) {
      const float4* nf4 = (const float4*)(nodef + (size_t)ei[ge] * 64 + dh);
#pragma unroll
      for (int j = 0; j < 8; ++j) {
        float4 v = nf4[j];
        int d = dh + j * 4;
        xs[(d + 0) * EPB + e] = v.x;
        xs[(d + 1) * EPB + e] = v.y;
        xs[(d + 2) * EPB + e] = v.z;
        xs[(d + 3) * EPB + e] = v.w;
      }
    } else {
#pragma unroll
      for (int j = 0; j < 8; ++j) {
        int d = dh + j * 4;
        xs[(d + 0) * EPB + e] = 0.f;
        xs[(d + 1) * EPB + e] = 0.f;
        xs[(d + 2) * EPB + e] = 0.f;
        xs[(d + 3) * EPB + e] = 0.f;
      }
    }
  }

  // ---- per-lane geometry
  const int lane = tid & 63, wv = tid >> 6;
  const int e0w = (wv & 1) * 64;        // wave edge base
  const int o0w = (wv >> 1) * 32;       // wave output base
  const int col = lane & 15;            // MFMA row/col index
  const int kg  = lane >> 4;            // k-group 0..3
  const int swz = (col & 7) << 3;       // LDS swizzle (same for A rows & W rows)

  // W2 prefetch pipeline registers (8 float4 = one 32 KB slab / 256 threads)
  float4 pf[8];
  const float4* w2base = (const float4*)net_w2;  // 4096*128 floats = 131072 float4; slab d = 2048 float4
  {
    const float4* s4 = w2base;  // d = 0
#pragma unroll
    for (int j = 0; j < 8; ++j) pf[j] = s4[j * 256 + tid];
  }

  f32x4 acc[4][2];
#pragma unroll
  for (int eb = 0; eb < 4; ++eb) { acc[eb][0] = 0.f; acc[eb][1] = 0.f; }

#pragma unroll 1
  for (int d = 0; d < 64; ++d) {
    __syncthreads();  // previous slab's Ws reads done (also covers A/x staging at d=0)
    // write slab d from prefetch regs (bf16, swizzled)
#pragma unroll
    for (int j = 0; j < 8; ++j) {
      int o = j * 8 + (tid >> 5), h4 = tid & 31;
      us4 p; p.x = f2bf(pf[j].x); p.y = f2bf(pf[j].y); p.z = f2bf(pf[j].z); p.w = f2bf(pf[j].w);
      *(us4*)&Ws[o * 128 + ((h4 * 4) ^ ((o & 7) << 3))] = p;
    }
    __syncthreads();
    // prefetch slab d+1 (overlaps compute below)
    if (d < 63) {
      const float4* s4 = w2base + (size_t)(d + 1) * 2048;
#pragma unroll
      for (int j = 0; j < 8; ++j) pf[j] = s4[j * 256 + tid];
    }

    // P init = b2 (C-in of the MFMA chain)
    const float b2v0 = net_b2[d * 64 + o0w + col];
    const float b2v1 = net_b2[d * 64 + o0w + 16 + col];
    f32x4 P[4][2];
#pragma unroll
    for (int eb = 0; eb < 4; ++eb) { P[eb][0] = b2v0; P[eb][1] = b2v1; }

#pragma unroll
    for (int kc = 0; kc < 4; ++kc) {
      const int hx = (kc * 32 + kg * 8) ^ swz;
      bf16x8 b0 = *(bf16x8*)&Ws[(o0w + col) * 128 + hx];
      bf16x8 b1 = *(bf16x8*)&Ws[(o0w + 16 + col) * 128 + hx];
#pragma unroll
      for (int eb = 0; eb < 4; ++eb) {
        bf16x8 a = *(bf16x8*)&As[(e0w + eb * 16 + col) * 128 + hx];
        P[eb][0] = __builtin_amdgcn_mfma_f32_16x16x32_bf16(a, b0, P[eb][0], 0, 0, 0);
        P[eb][1] = __builtin_amdgcn_mfma_f32_16x16x32_bf16(a, b1, P[eb][1], 0, 0, 0);
      }
    }

    // x-scale: acc += x[e,d] * P   (lane rows: e = e0w + eb*16 + kg*4 + r)
#pragma unroll
    for (int eb = 0; eb < 4; ++eb) {
      f32x4 xv = *(f32x4*)&xs[d * EPB + e0w + eb * 16 + kg * 4];
      acc[eb][0] += xv * P[eb][0];
      acc[eb][1] += xv * P[eb][1];
    }
  }

  // ---- scatter-add into aggr[dst]
#pragma unroll
  for (int eb = 0; eb < 4; ++eb) {
#pragma unroll
    for (int r = 0; r < 4; ++r) {
      int e = e0w + eb * 16 + kg * 4 + r;
      int ge = e0 + e;
      if (ge < N_EDGES_C) {
        int dn = ei[N_EDGES_C + ge];
        atomicAdd(&aggr[(size_t)dn * 64 + o0w + col],      acc[eb][0][r]);
        atomicAdd(&aggr[(size_t)dn * 64 + o0w + 16 + col], acc[eb][1][r]);
      }
    }
  }
}

// ---------------------------------------------------------------- root matmul + GRU
__global__ void node_update_kernel(
    const float* __restrict__ aggr, const float* __restrict__ invdeg,
    const float* __restrict__ conv_root, const float* __restrict__ conv_bias,
    const float* __restrict__ w_ih, const float* __restrict__ w_hh,
    const float* __restrict__ b_ih, const float* __restrict__ b_hh,
    float* __restrict__ h, float* __restrict__ out) {
  int n = blockIdx.x, o = threadIdx.x;
  __shared__ float outr[64], hr[64], mr[64];
  float hv = h[n * 64 + o];
  outr[o] = out[n * 64 + o];
  hr[o] = hv;
  __syncthreads();
  float root = 0.f;
#pragma unroll
  for (int d = 0; d < 64; ++d) root += outr[d] * conv_root[d * 64 + o];
  float m = lrelu(aggr[n * 64 + o] * invdeg[n] + root + conv_bias[o]);
  mr[o] = m;
  __syncthreads();
  float gi_r = b_ih[o], gi_z = b_ih[64 + o], gi_n = b_ih[128 + o];
  float gh_r = b_hh[o], gh_z = b_hh[64 + o], gh_n = b_hh[128 + o];
#pragma unroll 16
  for (int d = 0; d < 64; ++d) {
    float mv = mr[d], hvd = hr[d];
    gi_r += mv * w_ih[o * 64 + d];
    gi_z += mv * w_ih[(64 + o) * 64 + d];
    gi_n += mv * w_ih[(128 + o) * 64 + d];
    gh_r += hvd * w_hh[o * 64 + d];
    gh_z += hvd * w_hh[(64 + o) * 64 + d];
    gh_n += hvd * w_hh[(128 + o) * 64 + d];
  }
  float r = sigm(gi_r + gh_r), z = sigm(gi_z + gh_z);
  float nn = tanhf(gi_n + r * gh_n);
  float hn = (1.f - z) * nn + z * hv;
  h[n * 64 + o] = hn;
  out[n * 64 + o] = hn;
}

// ---------------------------------------------------------------- Set2Set LSTM cell
__global__ void lstm_kernel(const float* __restrict__ qstar,
    const float* __restrict__ w_ih, const float* __restrict__ w_hh,
    const float* __restrict__ b_ih, const float* __restrict__ b_hh,
    float* __restrict__ hl, float* __restrict__ cl) {
  int g = blockIdx.x, o = threadIdx.x;
  __shared__ float qs[128], hs[64];
  qs[o] = qstar[g * 128 + o];
  qs[64 + o] = qstar[g * 128 + 64 + o];
  float hv = hl[g * 64 + o];
  hs[o] = hv;
  __syncthreads();
  float gv[4];
#pragma unroll
  for (int k = 0; k < 4; ++k) {
    float s = b_ih[k * 64 + o] + b_hh[k * 64 + o];
    const float* wi = w_ih + (k * 64 + o) * 128;
    const float* wh = w_hh + (k * 64 + o) * 64;
#pragma unroll 16
    for (int j = 0; j < 128; ++j) s += qs[j] * wi[j];
#pragma unroll 16
    for (int j = 0; j < 64; ++j) s += hs[j] * wh[j];
    gv[k] = s;
  }
  float iv = sigm(gv[0]), fv = sigm(gv[1]), gg = tanhf(gv[2]), ov = sigm(gv[3]);
  float c = fv * cl[g * 64 + o] + iv * gg;
  float hn = ov * tanhf(c);
  cl[g * 64 + o] = c;
  hl[g * 64 + o] = hn;
}

// ---------------------------------------------------------------- segment softmax + readout
__global__ void attn_kernel(const float* __restrict__ out, const float* __restrict__ hl,
    const int* __restrict__ goff, float* __restrict__ ebuf, float* __restrict__ qstar) {
  int g = blockIdx.x, t = threadIdx.x;
  float qv = hl[g * 64 + t];
  int s0 = goff[g], s1 = goff[g + 1];
  float emax = -3.0e38f;
  for (int n = s0; n < s1; ++n) {
    float p = out[n * 64 + t] * qv;
#pragma unroll
    for (int off = 32; off > 0; off >>= 1) p += __shfl_down(p, off);
    float en = __shfl(p, 0);
    if (t == 0) ebuf[n] = en;
    emax = fmaxf(emax, en);
  }
  __syncthreads();  // drain ebuf writes before cross-lane reads
  float lsum = 0.f;
  for (int n = s0 + t; n < s1; n += 64) {
    float ex = __expf(ebuf[n] - emax);
    ebuf[n] = ex;
    lsum += ex;
  }
#pragma unroll
  for (int off = 32; off > 0; off >>= 1) lsum += __shfl_down(lsum, off);
  float denom = __shfl(lsum, 0);
  __syncthreads();
  float r = 0.f;
  for (int n = s0; n < s1; ++n) r += ebuf[n] * out[n * 64 + t];
  if (s1 > s0) r /= denom;
  qstar[g * 128 + t] = qv;
  qstar[g * 128 + 64 + t] = r;
}

// ---------------------------------------------------------------- final linear
__global__ void final_kernel(const float* __restrict__ qstar, const float* __restrict__ lw,
                             const float* __restrict__ lb, float* __restrict__ dout) {
  int b = blockIdx.x * blockDim.x + threadIdx.x;
  if (b >= N_GRAPHS_C) return;
  float s = lb[0];
#pragma unroll 16
  for (int j = 0; j < 128; ++j) s += qstar[b * 128 + j] * lw[j];
  dout[b] = s;
}

// ---------------------------------------------------------------- launch
extern "C" void kernel_launch(void* const* d_in, const int* in_sizes, int n_in,
                              void* d_out, int out_size, void* d_ws, size_t ws_size,
                              hipStream_t stream) {
  const float* x         = (const float*)d_in[0];
  const int*   ei        = (const int*)  d_in[1];
  const float* eattr     = (const float*)d_in[2];
  const int*   batch     = (const int*)  d_in[3];
  const float* lin0_w    = (const float*)d_in[4];
  const float* lin0_b    = (const float*)d_in[5];
  const float* net_w1    = (const float*)d_in[6];
  const float* net_b1    = (const float*)d_in[7];
  const float* net_w2    = (const float*)d_in[8];
  const float* net_b2    = (const float*)d_in[9];
  const float* conv_root = (const float*)d_in[10];
  const float* conv_bias = (const float*)d_in[11];
  const float* gru_w_ih  = (const float*)d_in[12];
  const float* gru_w_hh  = (const float*)d_in[13];
  const float* gru_b_ih  = (const float*)d_in[14];
  const float* gru_b_hh  = (const float*)d_in[15];
  const float* lstm_w_ih = (const float*)d_in[16];
  const float* lstm_w_hh = (const float*)d_in[17];
  const float* lstm_b_ih = (const float*)d_in[18];
  const float* lstm_b_hh = (const float*)d_in[19];
  const float* lin_w     = (const float*)d_in[20];
  const float* lin_b     = (const float*)d_in[21];

  // workspace layout (floats) — total ~19.5 MB
  float* ws    = (float*)d_ws;
  float* out   = ws;                  // 1,600,000
  float* h     = out + 1600000;       // 1,600,000
  float* aggr  = h + 1600000;         // 1,600,000
  float* deg   = aggr + 1600000;      // 25,000 (becomes inv_deg in place)
  float* ebuf  = deg + 25000;         // 25,000
  float* hl    = ebuf + 25000;        // 64,000
  float* cl    = hl + 64000;          // 64,000
  float* qstar = cl + 64000;          // 128,000
  int*   goff  = (int*)(qstar + 128000); // 1,001

  hipMemsetAsync(deg, 0, 25000 * sizeof(float), stream);
  hipMemsetAsync(hl, 0, (64000 + 64000 + 128000) * sizeof(float), stream);  // hl, cl, qstar

  lin0_kernel<<<N_NODES_C, 64, 0, stream>>>(x, lin0_w, lin0_b, out, h);
  deg_kernel<<<(N_EDGES_C + 255) / 256, 256, 0, stream>>>(ei, deg);
  invdeg_kernel<<<(N_NODES_C + 255) / 256, 256, 0, stream>>>(deg);
  goff_kernel<<<(N_GRAPHS_C + 256) / 256, 256, 0, stream>>>(batch, goff);

  for (int step = 0; step < 3; ++step) {
    hipMemsetAsync(aggr, 0, 1600000 * sizeof(float), stream);
    msg_kernel<<<(N_EDGES_C + EPB - 1) / EPB, 256, 0, stream>>>(
        out, ei, eattr, net_w1, net_b1, net_w2, net_b2, aggr);
    node_update_kernel<<<N_NODES_C, 64, 0, stream>>>(
        aggr, deg, conv_root, conv_bias, gru_w_ih, gru_w_hh, gru_b_ih, gru_b_hh, h, out);
  }

  for (int s = 0; s < 3; ++s) {
    lstm_kernel<<<N_GRAPHS_C, 64, 0, stream>>>(qstar, lstm_w_ih, lstm_w_hh, lstm_b_ih, lstm_b_hh, hl, cl);
    attn_kernel<<<N_GRAPHS_C, 64, 0, stream>>>(out, hl, goff, ebuf, qstar);
  }

  final_kernel<<<(N_GRAPHS_C + 127) / 128, 128, 0, stream>>>(qstar, lin_w, lin_b, (float*)d_out);
}

// Round 3
// 979.902 us; speedup vs baseline: 7.5634x; 1.8508x over previous
//
#include <hip/hip_runtime.h>
#include <math.h>

#define N_NODES_C  25000
#define N_EDGES_C  100000
#define N_GRAPHS_C 1000
#define EPB 128  // edges per block in msg_kernel

typedef __attribute__((ext_vector_type(8))) short   bf16x8;
typedef __attribute__((ext_vector_type(4))) unsigned short us4;
typedef __attribute__((ext_vector_type(4))) float   f32x4;

__device__ __forceinline__ float lrelu(float x) { return x > 0.f ? x : 0.01f * x; }
__device__ __forceinline__ float sigm(float x)  { return 1.f / (1.f + __expf(-x)); }
__device__ __forceinline__ unsigned short f2bf(float f) {
  union { float f; unsigned int u; } v; v.f = f;
  unsigned int r = v.u + 0x7fffu + ((v.u >> 16) & 1u);  // RNE
  return (unsigned short)(r >> 16);
}
__device__ __forceinline__ float bf2f(unsigned short u) {
  union { unsigned int i; float f; } v; v.i = ((unsigned int)u) << 16; return v.f;
}
__device__ __forceinline__ f32x4 MF(bf16x8 a, bf16x8 b, f32x4 c) {
  return __builtin_amdgcn_mfma_f32_16x16x32_bf16(a, b, c, 0, 0, 0);
}
// 8 floats -> hi/lo bf16x8 (split precision)
__device__ __forceinline__ void cvt8(f32x4 a, f32x4 b, bf16x8* hi, bf16x8* lo) {
  float v[8] = {a.x, a.y, a.z, a.w, b.x, b.y, b.z, b.w};
  bf16x8 H, L;
#pragma unroll
  for (int j = 0; j < 8; ++j) {
    unsigned short hh = f2bf(v[j]);
    H[j] = (short)hh;
    L[j] = (short)f2bf(v[j] - bf2f(hh));
  }
  *hi = H; *lo = L;
}

// ---------------------------------------------------------------- lin0 (LDS-staged weights)
__global__ __launch_bounds__(256) void lin0_kernel(const float* __restrict__ x,
                            const float* __restrict__ w, const float* __restrict__ b,
                            float* __restrict__ nodeF) {
  __shared__ float ws[64 * 15];  // pad 14->15: stride-15 is conflict-free-ish
  __shared__ float bs[64];
  __shared__ float xr[4][16];
  const int tid = threadIdx.x;
  for (int i = tid; i < 896; i += 256) { int o = i / 14, j = i % 14; ws[o * 15 + j] = w[i]; }
  if (tid < 64) bs[tid] = b[tid];
  const int nl = tid >> 6, o = tid & 63;
  const int n = blockIdx.x * 4 + nl;
  if (o < 14 && n < N_NODES_C) xr[nl][o] = x[n * 14 + o];
  __syncthreads();
  if (n < N_NODES_C) {
    float s = bs[o];
#pragma unroll
    for (int j = 0; j < 14; ++j) s += xr[nl][j] * ws[o * 15 + j];
    nodeF[n * 64 + o] = lrelu(s);
  }
}

// ---------------------------------------------------------------- degree
__global__ void deg_kernel(const int* __restrict__ ei, float* __restrict__ deg) {
  int e = blockIdx.x * blockDim.x + threadIdx.x;
  if (e < N_EDGES_C) atomicAdd(&deg[ei[N_EDGES_C + e]], 1.f);
}

__global__ void invdeg_kernel(float* __restrict__ deg) {
  int n = blockIdx.x * blockDim.x + threadIdx.x;
  if (n < N_NODES_C) { float v = deg[n]; deg[n] = v > 0.f ? 1.f / v : 0.f; }
}

// graph offsets via binary search over sorted batch
__global__ void goff_kernel(const int* __restrict__ batch, int* __restrict__ goff) {
  int g = blockIdx.x * blockDim.x + threadIdx.x;
  if (g > N_GRAPHS_C) return;
  int lo = 0, hi = N_NODES_C;
  while (lo < hi) { int mid = (lo + hi) >> 1; if (batch[mid] < g) lo = mid + 1; else hi = mid; }
  goff[g] = lo;
}

// ---------------------------------------------------------------- weight prep (once per launch)
// Rt[o][d] = conv_root[d][o]; Wi/Wh row-major [192][64]; all as bf16 hi + lo.
__global__ void prep_kernel(const float* __restrict__ conv_root,
                            const float* __restrict__ w_ih, const float* __restrict__ w_hh,
                            unsigned short* __restrict__ Rt_hi, unsigned short* __restrict__ Rt_lo,
                            unsigned short* __restrict__ Wi_hi, unsigned short* __restrict__ Wi_lo,
                            unsigned short* __restrict__ Wh_hi, unsigned short* __restrict__ Wh_lo) {
  int i = blockIdx.x * 256 + threadIdx.x;
  if (i < 4096) {
    int o = i >> 6, d = i & 63;
    float w = conv_root[d * 64 + o];
    unsigned short hi = f2bf(w);
    Rt_hi[i] = hi; Rt_lo[i] = f2bf(w - bf2f(hi));
  }
  if (i < 12288) {
    float w = w_ih[i];
    unsigned short hi = f2bf(w);
    Wi_hi[i] = hi; Wi_lo[i] = f2bf(w - bf2f(hi));
    w = w_hh[i];
    hi = f2bf(w);
    Wh_hi[i] = hi; Wh_lo[i] = f2bf(w - bf2f(hi));
  }
}

// ---------------------------------------------------------------- NNConv message + scatter (MFMA)
__global__ __launch_bounds__(256, 2) void msg_kernel(
    const float* __restrict__ nodef,     // [N,64]
    const int*   __restrict__ ei,        // [2,E]
    const float* __restrict__ eattr,     // [E,4]
    const float* __restrict__ net_w1,    // [128,4]
    const float* __restrict__ net_b1,    // [128]
    const float* __restrict__ net_w2,    // [4096,128]
    const float* __restrict__ net_b2,    // [4096]
    float* __restrict__ aggr)            // [N,64]
{
  __shared__ unsigned short As[EPB * 128];  // 32 KB  A[e][h], h ^= (e&7)<<3
  __shared__ unsigned short Ws[64 * 128];   // 16 KB  W2slab[o][h], h ^= (o&7)<<3
  __shared__ float          xs[64 * EPB];   // 32 KB  xs[d][e]

  const int tid = threadIdx.x;
  const int e0 = blockIdx.x * EPB;

  // ---- Stage A: edge-MLP hidden, 128 edges x 128 h (bf16, swizzled)
  {
    const int hh = tid & 127;
    const float w0 = net_w1[hh * 4 + 0], w1v = net_w1[hh * 4 + 1];
    const float w2v = net_w1[hh * 4 + 2], w3v = net_w1[hh * 4 + 3];
    const float bb = net_b1[hh];
    const int ebase = tid >> 7;  // 0 or 1
#pragma unroll 4
    for (int t = 0; t < 64; ++t) {
      int e = ebase + t * 2;
      int ge = e0 + e;
      float a = 0.f;
      if (ge < N_EDGES_C) {
        const float4 at = *(const float4*)(eattr + (size_t)ge * 4);
        a = bb + at.x * w0 + at.y * w1v + at.z * w2v + at.w * w3v;
        a = lrelu(a);
      }
      As[e * 128 + (hh ^ ((e & 7) << 3))] = f2bf(a);
    }
  }
  // ---- Stage x (transposed): xs[d][e] = nodef[src_e][d]
  {
    const int e = tid >> 1, dh = (tid & 1) * 32;
    int ge = e0 + e;
    if (ge < N_EDGES_C) {
      const float4* nf4 = (const float4*)(nodef + (size_t)ei[ge] * 64 + dh);
#pragma unroll
      for (int j = 0; j < 8; ++j) {
        float4 v = nf4[j];
        int d = dh + j * 4;
        xs[(d + 0) * EPB + e] = v.x;
        xs[(d + 1) * EPB + e] = v.y;
        xs[(d + 2) * EPB + e] = v.z;
        xs[(d + 3) * EPB + e] = v.w;
      }
    } else {
#pragma unroll
      for (int j = 0; j < 8; ++j) {
        int d = dh + j * 4;
        xs[(d + 0) * EPB + e] = 0.f;
        xs[(d + 1) * EPB + e] = 0.f;
        xs[(d + 2) * EPB + e] = 0.f;
        xs[(d + 3) * EPB + e] = 0.f;
      }
    }
  }

  const int lane = tid & 63, wv = tid >> 6;
  const int e0w = (wv & 1) * 64;
  const int o0w = (wv >> 1) * 32;
  const int col = lane & 15;
  const int kg  = lane >> 4;
  const int swz = (col & 7) << 3;

  float4 pf[8];
  const float4* w2base = (const float4*)net_w2;
  {
    const float4* s4 = w2base;
#pragma unroll
    for (int j = 0; j < 8; ++j) pf[j] = s4[j * 256 + tid];
  }

  f32x4 acc[4][2];
#pragma unroll
  for (int eb = 0; eb < 4; ++eb) { acc[eb][0] = 0.f; acc[eb][1] = 0.f; }

#pragma unroll 1
  for (int d = 0; d < 64; ++d) {
    __syncthreads();
#pragma unroll
    for (int j = 0; j < 8; ++j) {
      int o = j * 8 + (tid >> 5), h4 = tid & 31;
      us4 p; p.x = f2bf(pf[j].x); p.y = f2bf(pf[j].y); p.z = f2bf(pf[j].z); p.w = f2bf(pf[j].w);
      *(us4*)&Ws[o * 128 + ((h4 * 4) ^ ((o & 7) << 3))] = p;
    }
    __syncthreads();
    if (d < 63) {
      const float4* s4 = w2base + (size_t)(d + 1) * 2048;
#pragma unroll
      for (int j = 0; j < 8; ++j) pf[j] = s4[j * 256 + tid];
    }

    const float b2v0 = net_b2[d * 64 + o0w + col];
    const float b2v1 = net_b2[d * 64 + o0w + 16 + col];
    f32x4 P[4][2];
#pragma unroll
    for (int eb = 0; eb < 4; ++eb) { P[eb][0] = b2v0; P[eb][1] = b2v1; }

#pragma unroll
    for (int kc = 0; kc < 4; ++kc) {
      const int hx = (kc * 32 + kg * 8) ^ swz;
      bf16x8 b0 = *(bf16x8*)&Ws[(o0w + col) * 128 + hx];
      bf16x8 b1 = *(bf16x8*)&Ws[(o0w + 16 + col) * 128 + hx];
#pragma unroll
      for (int eb = 0; eb < 4; ++eb) {
        bf16x8 a = *(bf16x8*)&As[(e0w + eb * 16 + col) * 128 + hx];
        P[eb][0] = MF(a, b0, P[eb][0]);
        P[eb][1] = MF(a, b1, P[eb][1]);
      }
    }

#pragma unroll
    for (int eb = 0; eb < 4; ++eb) {
      f32x4 xv = *(f32x4*)&xs[d * EPB + e0w + eb * 16 + kg * 4];
      acc[eb][0] += xv * P[eb][0];
      acc[eb][1] += xv * P[eb][1];
    }
  }

#pragma unroll
  for (int eb = 0; eb < 4; ++eb) {
#pragma unroll
    for (int r = 0; r < 4; ++r) {
      int e = e0w + eb * 16 + kg * 4 + r;
      int ge = e0 + e;
      if (ge < N_EDGES_C) {
        int dn = ei[N_EDGES_C + ge];
        atomicAdd(&aggr[(size_t)dn * 64 + o0w + col],      acc[eb][0][r]);
        atomicAdd(&aggr[(size_t)dn * 64 + o0w + 16 + col], acc[eb][1][r]);
      }
    }
  }
}

// ---------------------------------------------------------------- root matmul + GRU (MFMA, split-bf16)
// Block: 64 nodes, 4 waves x 16 nodes. All GEMMs D[n,o] = sum_d A[n,d]*W[o,d].
__global__ __launch_bounds__(256, 1) void node_update_kernel(
    const float* __restrict__ aggr, const float* __restrict__ invdeg,
    const unsigned short* __restrict__ Rt_hi, const unsigned short* __restrict__ Rt_lo,
    const unsigned short* __restrict__ Wi_hi, const unsigned short* __restrict__ Wi_lo,
    const unsigned short* __restrict__ Wh_hi, const unsigned short* __restrict__ Wh_lo,
    const float* __restrict__ conv_bias,
    const float* __restrict__ b_ih, const float* __restrict__ b_hh,
    float* __restrict__ nodeF)
{
  __shared__ unsigned short m_hi[4][16 * 64];  // per-wave m tile, swizzled d ^= (nl&7)<<3
  __shared__ unsigned short m_lo[4][16 * 64];

  const int tid = threadIdx.x, lane = tid & 63, wv = tid >> 6;
  const int col = lane & 15, kg = lane >> 4;
  const int nwb = blockIdx.x * 64 + wv * 16;  // wave node base

  // ---- A fragments: nodeF rows (node = nwb+col), split to hi/lo. (out == h)
  int arow = nwb + col; if (arow >= N_NODES_C) arow = N_NODES_C - 1;
  bf16x8 nf_hi[2], nf_lo[2];
#pragma unroll
  for (int kc = 0; kc < 2; ++kc) {
    int doff = kc * 32 + kg * 8;
    f32x4 v0 = *(const f32x4*)(nodeF + (size_t)arow * 64 + doff);
    f32x4 v1 = *(const f32x4*)(nodeF + (size_t)arow * 64 + doff + 4);
    cvt8(v0, v1, &nf_hi[kc], &nf_lo[kc]);
  }

  // ---- Phase 1: root = nodeF @ Rt^T, C-init = conv_bias
  f32x4 racc[4];
#pragma unroll
  for (int t = 0; t < 4; ++t) racc[t] = conv_bias[t * 16 + col];
#pragma unroll
  for (int t = 0; t < 4; ++t) {
#pragma unroll
    for (int kc = 0; kc < 2; ++kc) {
      int off = (t * 16 + col) * 64 + kc * 32 + kg * 8;
      bf16x8 bh = *(const bf16x8*)(Rt_hi + off);
      bf16x8 bl = *(const bf16x8*)(Rt_lo + off);
      racc[t] = MF(nf_hi[kc], bh, racc[t]);
      racc[t] = MF(nf_hi[kc], bl, racc[t]);
      racc[t] = MF(nf_lo[kc], bh, racc[t]);
    }
  }

  // ---- Epilogue 1: m = lrelu(aggr*invdeg + racc); write m hi/lo to wave-private LDS
  float invd[4]; int nrow[4];
#pragma unroll
  for (int r = 0; r < 4; ++r) {
    int nn = nwb + kg * 4 + r; nrow[r] = nn;
    invd[r] = (nn < N_NODES_C) ? invdeg[nn] : 0.f;
  }
#pragma unroll
  for (int t = 0; t < 4; ++t) {
#pragma unroll
    for (int r = 0; r < 4; ++r) {
      int nn = nrow[r];
      float ag = (nn < N_NODES_C) ? aggr[(size_t)nn * 64 + t * 16 + col] : 0.f;
      float mval = lrelu(ag * invd[r] + racc[t][r]);
      int nl = kg * 4 + r;
      int dsw = (t * 16 + col) ^ ((nl & 7) << 3);
      unsigned short mh = f2bf(mval);
      m_hi[wv][nl * 64 + dsw] = mh;
      m_lo[wv][nl * 64 + dsw] = f2bf(mval - bf2f(mh));
    }
  }
  __syncthreads();  // drain LDS writes (cross-lane within wave)

  // ---- Phase 2 A-frags: m from LDS (swizzled)
  bf16x8 ma_hi[2], ma_lo[2];
#pragma unroll
  for (int kc = 0; kc < 2; ++kc) {
    int doff = (kc * 32 + kg * 8) ^ ((col & 7) << 3);
    ma_hi[kc] = *(const bf16x8*)&m_hi[wv][col * 64 + doff];
    ma_lo[kc] = *(const bf16x8*)&m_lo[wv][col * 64 + doff];
  }

  // ---- Phase 2: gi = m @ Wi^T + b_ih ; gh = h @ Wh^T + b_hh   (h frag == nf frag)
  f32x4 gi[12], gh[12];
#pragma unroll
  for (int t = 0; t < 12; ++t) {
    gi[t] = b_ih[t * 16 + col];
    gh[t] = b_hh[t * 16 + col];
  }
#pragma unroll
  for (int t = 0; t < 12; ++t) {
#pragma unroll
    for (int kc = 0; kc < 2; ++kc) {
      int off = (t * 16 + col) * 64 + kc * 32 + kg * 8;
      bf16x8 bh = *(const bf16x8*)(Wi_hi + off);
      bf16x8 bl = *(const bf16x8*)(Wi_lo + off);
      gi[t] = MF(ma_hi[kc], bh, gi[t]);
      gi[t] = MF(ma_hi[kc], bl, gi[t]);
      gi[t] = MF(ma_lo[kc], bh, gi[t]);
      bh = *(const bf16x8*)(Wh_hi + off);
      bl = *(const bf16x8*)(Wh_lo + off);
      gh[t] = MF(nf_hi[kc], bh, gh[t]);
      gh[t] = MF(nf_hi[kc], bl, gh[t]);
      gh[t] = MF(nf_lo[kc], bh, gh[t]);
    }
  }

  // ---- Epilogue 2: GRU combine (gates r,z,n), write h (== out) back to nodeF
#pragma unroll
  for (int t = 0; t < 4; ++t) {
#pragma unroll
    for (int r = 0; r < 4; ++r) {
      int nn = nrow[r];
      if (nn >= N_NODES_C) continue;
      size_t idx = (size_t)nn * 64 + t * 16 + col;
      float hv = nodeF[idx];
      float rr = sigm(gi[t][r] + gh[t][r]);
      float zz = sigm(gi[t + 4][r] + gh[t + 4][r]);
      float nv = tanhf(gi[t + 8][r] + rr * gh[t + 8][r]);
      nodeF[idx] = (1.f - zz) * nv + zz * hv;
    }
  }
}

// ---------------------------------------------------------------- Set2Set LSTM cell
__global__ void lstm_kernel(const float* __restrict__ qstar,
    const float* __restrict__ w_ih, const float* __restrict__ w_hh,
    const float* __restrict__ b_ih, const float* __restrict__ b_hh,
    float* __restrict__ hl, float* __restrict__ cl) {
  int g = blockIdx.x, o = threadIdx.x;
  __shared__ float qs[128], hs[64];
  qs[o] = qstar[g * 128 + o];
  qs[64 + o] = qstar[g * 128 + 64 + o];
  float hv = hl[g * 64 + o];
  hs[o] = hv;
  __syncthreads();
  float gv[4];
#pragma unroll
  for (int k = 0; k < 4; ++k) {
    float s = b_ih[k * 64 + o] + b_hh[k * 64 + o];
    const float* wi = w_ih + (k * 64 + o) * 128;
    const float* wh = w_hh + (k * 64 + o) * 64;
#pragma unroll 16
    for (int j = 0; j < 128; ++j) s += qs[j] * wi[j];
#pragma unroll 16
    for (int j = 0; j < 64; ++j) s += hs[j] * wh[j];
    gv[k] = s;
  }
  float iv = sigm(gv[0]), fv = sigm(gv[1]), gg = tanhf(gv[2]), ov = sigm(gv[3]);
  float c = fv * cl[g * 64 + o] + iv * gg;
  float hn = ov * tanhf(c);
  cl[g * 64 + o] = c;
  hl[g * 64 + o] = hn;
}

// ---------------------------------------------------------------- segment softmax + readout
__global__ void attn_kernel(const float* __restrict__ out, const float* __restrict__ hl,
    const int* __restrict__ goff, float* __restrict__ ebuf, float* __restrict__ qstar) {
  int g = blockIdx.x, t = threadIdx.x;
  float qv = hl[g * 64 + t];
  int s0 = goff[g], s1 = goff[g + 1];
  float emax = -3.0e38f;
  for (int n = s0; n < s1; ++n) {
    float p = out[n * 64 + t] * qv;
#pragma unroll
    for (int off = 32; off > 0; off >>= 1) p += __shfl_down(p, off);
    float en = __shfl(p, 0);
    if (t == 0) ebuf[n] = en;
    emax = fmaxf(emax, en);
  }
  __syncthreads();
  float lsum = 0.f;
  for (int n = s0 + t; n < s1; n += 64) {
    float ex = __expf(ebuf[n] - emax);
    ebuf[n] = ex;
    lsum += ex;
  }
#pragma unroll
  for (int off = 32; off > 0; off >>= 1) lsum += __shfl_down(lsum, off);
  float denom = __shfl(lsum, 0);
  __syncthreads();
  float r = 0.f;
  for (int n = s0; n < s1; ++n) r += ebuf[n] * out[n * 64 + t];
  if (s1 > s0) r /= denom;
  qstar[g * 128 + t] = qv;
  qstar[g * 128 + 64 + t] = r;
}

// ---------------------------------------------------------------- final linear
__global__ void final_kernel(const float* __restrict__ qstar, const float* __restrict__ lw,
                             const float* __restrict__ lb, float* __restrict__ dout) {
  int b = blockIdx.x * blockDim.x + threadIdx.x;
  if (b >= N_GRAPHS_C) return;
  float s = lb[0];
#pragma unroll 16
  for (int j = 0; j < 128; ++j) s += qstar[b * 128 + j] * lw[j];
  dout[b] = s;
}

// ---------------------------------------------------------------- launch
extern "C" void kernel_launch(void* const* d_in, const int* in_sizes, int n_in,
                              void* d_out, int out_size, void* d_ws, size_t ws_size,
                              hipStream_t stream) {
  const float* x         = (const float*)d_in[0];
  const int*   ei        = (const int*)  d_in[1];
  const float* eattr     = (const float*)d_in[2];
  const int*   batch     = (const int*)  d_in[3];
  const float* lin0_w    = (const float*)d_in[4];
  const float* lin0_b    = (const float*)d_in[5];
  const float* net_w1    = (const float*)d_in[6];
  const float* net_b1    = (const float*)d_in[7];
  const float* net_w2    = (const float*)d_in[8];
  const float* net_b2    = (const float*)d_in[9];
  const float* conv_root = (const float*)d_in[10];
  const float* conv_bias = (const float*)d_in[11];
  const float* gru_w_ih  = (const float*)d_in[12];
  const float* gru_w_hh  = (const float*)d_in[13];
  const float* gru_b_ih  = (const float*)d_in[14];
  const float* gru_b_hh  = (const float*)d_in[15];
  const float* lstm_w_ih = (const float*)d_in[16];
  const float* lstm_w_hh = (const float*)d_in[17];
  const float* lstm_b_ih = (const float*)d_in[18];
  const float* lstm_b_hh = (const float*)d_in[19];
  const float* lin_w     = (const float*)d_in[20];
  const float* lin_b     = (const float*)d_in[21];

  // workspace layout (floats), ~14.2 MB total
  float* ws    = (float*)d_ws;
  float* nodeF = ws;                   // 1,600,000  (out == h merged)
  float* aggr  = nodeF + 1600000;      // 1,600,000
  float* deg   = aggr + 1600000;       // 25,000
  float* ebuf  = deg + 25000;          // 25,000
  float* hl    = ebuf + 25000;         // 64,000
  float* cl    = hl + 64000;           // 64,000
  float* qstar = cl + 64000;           // 128,000
  int*   goff  = (int*)(qstar + 128000);      // 1,024 (padded)
  unsigned short* wprep = (unsigned short*)(goff + 1024);
  unsigned short* Rt_hi = wprep;               // 4096
  unsigned short* Rt_lo = Rt_hi + 4096;        // 4096
  unsigned short* Wi_hi = Rt_lo + 4096;        // 12288
  unsigned short* Wi_lo = Wi_hi + 12288;       // 12288
  unsigned short* Wh_hi = Wi_lo + 12288;       // 12288
  unsigned short* Wh_lo = Wh_hi + 12288;       // 12288

  hipMemsetAsync(deg, 0, 25000 * sizeof(float), stream);
  hipMemsetAsync(hl, 0, (64000 + 64000 + 128000) * sizeof(float), stream);  // hl, cl, qstar

  lin0_kernel<<<(N_NODES_C + 3) / 4, 256, 0, stream>>>(x, lin0_w, lin0_b, nodeF);
  deg_kernel<<<(N_EDGES_C + 255) / 256, 256, 0, stream>>>(ei, deg);
  invdeg_kernel<<<(N_NODES_C + 255) / 256, 256, 0, stream>>>(deg);
  goff_kernel<<<(N_GRAPHS_C + 256) / 256, 256, 0, stream>>>(batch, goff);
  prep_kernel<<<48, 256, 0, stream>>>(conv_root, gru_w_ih, gru_w_hh,
                                      Rt_hi, Rt_lo, Wi_hi, Wi_lo, Wh_hi, Wh_lo);

  for (int step = 0; step < 3; ++step) {
    hipMemsetAsync(aggr, 0, 1600000 * sizeof(float), stream);
    msg_kernel<<<(N_EDGES_C + EPB - 1) / EPB, 256, 0, stream>>>(
        nodeF, ei, eattr, net_w1, net_b1, net_w2, net_b2, aggr);
    node_update_kernel<<<(N_NODES_C + 63) / 64, 256, 0, stream>>>(
        aggr, deg, Rt_hi, Rt_lo, Wi_hi, Wi_lo, Wh_hi, Wh_lo,
        conv_bias, gru_b_ih, gru_b_hh, nodeF);
  }

  for (int s = 0; s < 3; ++s) {
    lstm_kernel<<<N_GRAPHS_C, 64, 0, stream>>>(qstar, lstm_w_ih, lstm_w_hh, lstm_b_ih, lstm_b_hh, hl, cl);
    attn_kernel<<<N_GRAPHS_C, 64, 0, stream>>>(nodeF, hl, goff, ebuf, qstar);
  }

  final_kernel<<<(N_GRAPHS_C + 127) / 128, 128, 0, stream>>>(qstar, lin_w, lin_b, (float*)d_out);
}

// Round 4
// 733.750 us; speedup vs baseline: 10.1007x; 1.3355x over previous
//
#include <hip/hip_runtime.h>
#include <math.h>

#define N_NODES_C  25000
#define N_EDGES_C  100000
#define N_GRAPHS_C 1000
#define EPB 128  // edges per block in msg_kernel

typedef __attribute__((ext_vector_type(8))) short   bf16x8;
typedef __attribute__((ext_vector_type(8))) _Float16 f16x8;
typedef __attribute__((ext_vector_type(4))) float   f32x4;

__device__ __forceinline__ float lrelu(float x) { return x > 0.f ? x : 0.01f * x; }
__device__ __forceinline__ float sigm(float x)  { return 1.f / (1.f + __expf(-x)); }
__device__ __forceinline__ unsigned short f2bf(float f) {
  union { float f; unsigned int u; } v; v.f = f;
  unsigned int r = v.u + 0x7fffu + ((v.u >> 16) & 1u);  // RNE
  return (unsigned short)(r >> 16);
}
__device__ __forceinline__ float bf2f(unsigned short u) {
  union { unsigned int i; float f; } v; v.i = ((unsigned int)u) << 16; return v.f;
}
__device__ __forceinline__ f32x4 MF(bf16x8 a, bf16x8 b, f32x4 c) {
  return __builtin_amdgcn_mfma_f32_16x16x32_bf16(a, b, c, 0, 0, 0);
}
__device__ __forceinline__ f32x4 MFH(f16x8 a, f16x8 b, f32x4 c) {
  return __builtin_amdgcn_mfma_f32_16x16x32_f16(a, b, c, 0, 0, 0);
}
// 8 floats -> hi/lo bf16x8 (split precision)
__device__ __forceinline__ void cvt8(f32x4 a, f32x4 b, bf16x8* hi, bf16x8* lo) {
  float v[8] = {a.x, a.y, a.z, a.w, b.x, b.y, b.z, b.w};
  bf16x8 H, L;
#pragma unroll
  for (int j = 0; j < 8; ++j) {
    unsigned short hh = f2bf(v[j]);
    H[j] = (short)hh;
    L[j] = (short)f2bf(v[j] - bf2f(hh));
  }
  *hi = H; *lo = L;
}

// ---------------------------------------------------------------- lin0 (LDS-staged weights)
__global__ __launch_bounds__(256) void lin0_kernel(const float* __restrict__ x,
                            const float* __restrict__ w, const float* __restrict__ b,
                            float* __restrict__ nodeF) {
  __shared__ float ws[64 * 15];
  __shared__ float bs[64];
  __shared__ float xr[4][16];
  const int tid = threadIdx.x;
  for (int i = tid; i < 896; i += 256) { int o = i / 14, j = i % 14; ws[o * 15 + j] = w[i]; }
  if (tid < 64) bs[tid] = b[tid];
  const int nl = tid >> 6, o = tid & 63;
  const int n = blockIdx.x * 4 + nl;
  if (o < 14 && n < N_NODES_C) xr[nl][o] = x[n * 14 + o];
  __syncthreads();
  if (n < N_NODES_C) {
    float s = bs[o];
#pragma unroll
    for (int j = 0; j < 14; ++j) s += xr[nl][j] * ws[o * 15 + j];
    nodeF[n * 64 + o] = lrelu(s);
  }
}

// ---------------------------------------------------------------- degree
__global__ void deg_kernel(const int* __restrict__ ei, float* __restrict__ deg) {
  int e = blockIdx.x * blockDim.x + threadIdx.x;
  if (e < N_EDGES_C) atomicAdd(&deg[ei[N_EDGES_C + e]], 1.f);
}

__global__ void invdeg_kernel(float* __restrict__ deg) {
  int n = blockIdx.x * blockDim.x + threadIdx.x;
  if (n < N_NODES_C) { float v = deg[n]; deg[n] = v > 0.f ? 1.f / v : 0.f; }
}

// graph offsets via binary search over sorted batch
__global__ void goff_kernel(const int* __restrict__ batch, int* __restrict__ goff) {
  int g = blockIdx.x * blockDim.x + threadIdx.x;
  if (g > N_GRAPHS_C) return;
  int lo = 0, hi = N_NODES_C;
  while (lo < hi) { int mid = (lo + hi) >> 1; if (batch[mid] < g) lo = mid + 1; else hi = mid; }
  goff[g] = lo;
}

// ---------------------------------------------------------------- GRU weight prep (once per launch)
__global__ void prep_kernel(const float* __restrict__ conv_root,
                            const float* __restrict__ w_ih, const float* __restrict__ w_hh,
                            unsigned short* __restrict__ Rt_hi, unsigned short* __restrict__ Rt_lo,
                            unsigned short* __restrict__ Wi_hi, unsigned short* __restrict__ Wi_lo,
                            unsigned short* __restrict__ Wh_hi, unsigned short* __restrict__ Wh_lo) {
  int i = blockIdx.x * 256 + threadIdx.x;
  if (i < 4096) {
    int o = i >> 6, d = i & 63;
    float w = conv_root[d * 64 + o];
    unsigned short hi = f2bf(w);
    Rt_hi[i] = hi; Rt_lo[i] = f2bf(w - bf2f(hi));
  }
  if (i < 12288) {
    float w = w_ih[i];
    unsigned short hi = f2bf(w);
    Wi_hi[i] = hi; Wi_lo[i] = f2bf(w - bf2f(hi));
    w = w_hh[i];
    hi = f2bf(w);
    Wh_hi[i] = hi; Wh_lo[i] = f2bf(w - bf2f(hi));
  }
}

// ---------------------------------------------------------------- W2 prep: frag-major fp16 image
// Wp[i], i = (((d*4 + oh)*4 + kc)*64 + lane)*8 + j  <-  W2[(d*64 + o)*128 + h]
//   o = oh*16 + (lane&15), h = kc*32 + (lane>>4)*8 + j
// B2p[i], i = ((oh*2 + kc2)*64 + lane)*8 + j        <-  b2[d*64 + o]
//   o = oh*16 + (lane&15), d = kc2*32 + (lane>>4)*8 + j
__global__ __launch_bounds__(256) void prep_w2_kernel(
    const float* __restrict__ net_w2, const float* __restrict__ net_b2,
    _Float16* __restrict__ Wp, _Float16* __restrict__ B2p) {
  int i = blockIdx.x * 256 + threadIdx.x;  // < 524288
  {
    int j = i & 7, l = (i >> 3) & 63, kc = (i >> 9) & 3, oh = (i >> 11) & 3, d = i >> 13;
    int col = l & 15, kg = l >> 4;
    int o = oh * 16 + col, h = kc * 32 + kg * 8 + j;
    Wp[i] = (_Float16)net_w2[(d * 64 + o) * 128 + h];
  }
  if (i < 4096) {
    int j = i & 7, l = (i >> 3) & 63, kc2 = (i >> 9) & 1, oh = (i >> 10) & 3;
    int col = l & 15, kg = l >> 4;
    int o = oh * 16 + col, d = kc2 * 32 + kg * 8 + j;
    B2p[i] = (_Float16)net_b2[d * 64 + o];
  }
}

// ---------------------------------------------------------------- NNConv message + scatter
// msg = U @ W'^T + x @ B2,  U[e, d*128+h] = x[e,d]*A[e,h]  (K=8192, fp16 in / fp32 acc)
// Block: 128 edges, 4 waves (wave tile 64e x 32o). Barrier-free d-loop:
// A-frags register-resident, B-frags double-buffered from L2 (frag-major Wp).
__global__ __launch_bounds__(256, 2) void msg_kernel(
    const float* __restrict__ nodef,     // [N,64]
    const int*   __restrict__ ei,        // [2,E]
    const float* __restrict__ eattr,     // [E,4]
    const float* __restrict__ net_w1,    // [128,4]
    const float* __restrict__ net_b1,    // [128]
    const _Float16* __restrict__ Wp,     // frag-major W2 fp16 (1 MB)
    const _Float16* __restrict__ B2p,    // frag-major b2 fp16 (8 KB)
    float* __restrict__ aggr)            // [N,64]
{
  __shared__ _Float16 As[EPB * 128];   // 32 KB  A[e][h], h ^= (e&7)<<3
  __shared__ _Float16 xs[64 * EPB];    // 16 KB  xs[d][e]
  __shared__ _Float16 xsT[EPB * 64];   // 16 KB  xsT[e][d], d ^= (e&7)<<3

  const int tid = threadIdx.x;
  const int e0 = blockIdx.x * EPB;

  // ---- Stage A: edge-MLP hidden, 128 edges x 128 h (fp16, swizzled)
  {
    const int hh = tid & 127;
    const float w0 = net_w1[hh * 4 + 0], w1v = net_w1[hh * 4 + 1];
    const float w2v = net_w1[hh * 4 + 2], w3v = net_w1[hh * 4 + 3];
    const float bb = net_b1[hh];
    const int ebase = tid >> 7;  // 0 or 1
#pragma unroll 4
    for (int t = 0; t < 64; ++t) {
      int e = ebase + t * 2;
      int ge = e0 + e;
      float a = 0.f;
      if (ge < N_EDGES_C) {
        const float4 at = *(const float4*)(eattr + (size_t)ge * 4);
        a = bb + at.x * w0 + at.y * w1v + at.z * w2v + at.w * w3v;
        a = lrelu(a);
      }
      As[e * 128 + (hh ^ ((e & 7) << 3))] = (_Float16)a;
    }
  }
  // ---- Stage x: xs[d][e] scalar + xsT[e][d] frag (fp16)
  {
    const int e = tid >> 1, dh = (tid & 1) * 32;
    int ge = e0 + e;
    const int esw = (e & 7) << 3;
#pragma unroll
    for (int jb = 0; jb < 4; ++jb) {   // 8 d's per jb
      int d = dh + jb * 8;
      float4 v0, v1;
      if (ge < N_EDGES_C) {
        const float4* nf4 = (const float4*)(nodef + (size_t)ei[ge] * 64 + d);
        v0 = nf4[0]; v1 = nf4[1];
      } else {
        v0 = make_float4(0.f, 0.f, 0.f, 0.f); v1 = v0;
      }
      f16x8 pk;
      pk[0] = (_Float16)v0.x; pk[1] = (_Float16)v0.y; pk[2] = (_Float16)v0.z; pk[3] = (_Float16)v0.w;
      pk[4] = (_Float16)v1.x; pk[5] = (_Float16)v1.y; pk[6] = (_Float16)v1.z; pk[7] = (_Float16)v1.w;
      *(f16x8*)&xsT[e * 64 + (d ^ esw)] = pk;
#pragma unroll
      for (int j = 0; j < 8; ++j) xs[(d + j) * EPB + e] = pk[j];
    }
  }

  const int lane = tid & 63, wv = tid >> 6;
  const int e0w = (wv & 1) * 64;
  const int o0w = (wv >> 1) * 32;
  const int col = lane & 15;
  const int kg  = lane >> 4;
  const int swz = (col & 7) << 3;
  const int oh0 = o0w >> 4;           // 0 or 2

  __syncthreads();  // staging done; d-loop below is barrier-free (LDS read-only)

  // ---- A-frags register-resident: Af[eb][kc]
  f16x8 Af[4][4];
#pragma unroll
  for (int eb = 0; eb < 4; ++eb)
#pragma unroll
    for (int kc = 0; kc < 4; ++kc)
      Af[eb][kc] = *(const f16x8*)&As[(e0w + eb * 16 + col) * 128 + ((kc * 32 + kg * 8) ^ swz)];

  // ---- acc init: b2 term  (acc[eb][ob] over 16 MFMA)
  f32x4 acc[4][2];
#pragma unroll
  for (int eb = 0; eb < 4; ++eb) { acc[eb][0] = 0.f; acc[eb][1] = 0.f; }
#pragma unroll
  for (int ob = 0; ob < 2; ++ob)
#pragma unroll
    for (int kc2 = 0; kc2 < 2; ++kc2) {
      f16x8 b2f = *(const f16x8*)(B2p + (((oh0 + ob) * 2 + kc2) * 64 + lane) * 8);
#pragma unroll
      for (int eb = 0; eb < 4; ++eb) {
        f16x8 xf = *(const f16x8*)&xsT[(e0w + eb * 16 + col) * 64 + ((kc2 * 32 + kg * 8) ^ swz)];
        acc[eb][ob] = MFH(xf, b2f, acc[eb][ob]);
      }
    }

  // ---- main d-loop: barrier-free, B double-buffered from L2
  f16x8 B0[8], B1[8];
#define LOADB(BUF, dd)                                                              \
  {                                                                                 \
    _Pragma("unroll")                                                               \
    for (int q = 0; q < 8; ++q) {                                                   \
      int ob_ = q >> 2, kc_ = q & 3;                                                \
      BUF[q] = *(const f16x8*)(Wp + ((((dd) * 4 + oh0 + ob_) * 4 + kc_) * 64 + lane) * 8); \
    }                                                                               \
  }
#define SLAB(BUF, dd)                                                               \
  {                                                                                 \
    _Pragma("unroll")                                                               \
    for (int eb = 0; eb < 4; ++eb) {                                                \
      _Float16 xv = xs[(dd) * EPB + e0w + eb * 16 + col];                           \
      f16x8 xd = {xv, xv, xv, xv, xv, xv, xv, xv};                                  \
      _Pragma("unroll")                                                             \
      for (int kc = 0; kc < 4; ++kc) {                                              \
        f16x8 U = Af[eb][kc] * xd;                                                  \
        acc[eb][0] = MFH(U, BUF[kc], acc[eb][0]);                                   \
        acc[eb][1] = MFH(U, BUF[4 + kc], acc[eb][1]);                               \
      }                                                                             \
    }                                                                               \
  }

  LOADB(B0, 0);
#pragma unroll 1
  for (int d = 0; d < 64; d += 2) {
    LOADB(B1, d + 1);
    SLAB(B0, d);
    if (d + 2 < 64) LOADB(B0, d + 2);
    SLAB(B1, d + 1);
  }
#undef LOADB
#undef SLAB

  // ---- scatter-add into aggr[dst]
#pragma unroll
  for (int eb = 0; eb < 4; ++eb) {
#pragma unroll
    for (int r = 0; r < 4; ++r) {
      int e = e0w + eb * 16 + kg * 4 + r;
      int ge = e0 + e;
      if (ge < N_EDGES_C) {
        int dn = ei[N_EDGES_C + ge];
        atomicAdd(&aggr[(size_t)dn * 64 + o0w + col],      acc[eb][0][r]);
        atomicAdd(&aggr[(size_t)dn * 64 + o0w + 16 + col], acc[eb][1][r]);
      }
    }
  }
}

// ---------------------------------------------------------------- root matmul + GRU (MFMA, split-bf16)
__global__ __launch_bounds__(256, 1) void node_update_kernel(
    const float* __restrict__ aggr, const float* __restrict__ invdeg,
    const unsigned short* __restrict__ Rt_hi, const unsigned short* __restrict__ Rt_lo,
    const unsigned short* __restrict__ Wi_hi, const unsigned short* __restrict__ Wi_lo,
    const unsigned short* __restrict__ Wh_hi, const unsigned short* __restrict__ Wh_lo,
    const float* __restrict__ conv_bias,
    const float* __restrict__ b_ih, const float* __restrict__ b_hh,
    float* __restrict__ nodeF)
{
  __shared__ unsigned short m_hi[4][16 * 64];
  __shared__ unsigned short m_lo[4][16 * 64];

  const int tid = threadIdx.x, lane = tid & 63, wv = tid >> 6;
  const int col = lane & 15, kg = lane >> 4;
  const int nwb = blockIdx.x * 64 + wv * 16;

  int arow = nwb + col; if (arow >= N_NODES_C) arow = N_NODES_C - 1;
  bf16x8 nf_hi[2], nf_lo[2];
#pragma unroll
  for (int kc = 0; kc < 2; ++kc) {
    int doff = kc * 32 + kg * 8;
    f32x4 v0 = *(const f32x4*)(nodeF + (size_t)arow * 64 + doff);
    f32x4 v1 = *(const f32x4*)(nodeF + (size_t)arow * 64 + doff + 4);
    cvt8(v0, v1, &nf_hi[kc], &nf_lo[kc]);
  }

  f32x4 racc[4];
#pragma unroll
  for (int t = 0; t < 4; ++t) racc[t] = conv_bias[t * 16 + col];
#pragma unroll
  for (int t = 0; t < 4; ++t) {
#pragma unroll
    for (int kc = 0; kc < 2; ++kc) {
      int off = (t * 16 + col) * 64 + kc * 32 + kg * 8;
      bf16x8 bh = *(const bf16x8*)(Rt_hi + off);
      bf16x8 bl = *(const bf16x8*)(Rt_lo + off);
      racc[t] = MF(nf_hi[kc], bh, racc[t]);
      racc[t] = MF(nf_hi[kc], bl, racc[t]);
      racc[t] = MF(nf_lo[kc], bh, racc[t]);
    }
  }

  float invd[4]; int nrow[4];
#pragma unroll
  for (int r = 0; r < 4; ++r) {
    int nn = nwb + kg * 4 + r; nrow[r] = nn;
    invd[r] = (nn < N_NODES_C) ? invdeg[nn] : 0.f;
  }
#pragma unroll
  for (int t = 0; t < 4; ++t) {
#pragma unroll
    for (int r = 0; r < 4; ++r) {
      int nn = nrow[r];
      float ag = (nn < N_NODES_C) ? aggr[(size_t)nn * 64 + t * 16 + col] : 0.f;
      float mval = lrelu(ag * invd[r] + racc[t][r]);
      int nl = kg * 4 + r;
      int dsw = (t * 16 + col) ^ ((nl & 7) << 3);
      unsigned short mh = f2bf(mval);
      m_hi[wv][nl * 64 + dsw] = mh;
      m_lo[wv][nl * 64 + dsw] = f2bf(mval - bf2f(mh));
    }
  }
  __syncthreads();

  bf16x8 ma_hi[2], ma_lo[2];
#pragma unroll
  for (int kc = 0; kc < 2; ++kc) {
    int doff = (kc * 32 + kg * 8) ^ ((col & 7) << 3);
    ma_hi[kc] = *(const bf16x8*)&m_hi[wv][col * 64 + doff];
    ma_lo[kc] = *(const bf16x8*)&m_lo[wv][col * 64 + doff];
  }

  f32x4 gi[12], gh[12];
#pragma unroll
  for (int t = 0; t < 12; ++t) {
    gi[t] = b_ih[t * 16 + col];
    gh[t] = b_hh[t * 16 + col];
  }
#pragma unroll
  for (int t = 0; t < 12; ++t) {
#pragma unroll
    for (int kc = 0; kc < 2; ++kc) {
      int off = (t * 16 + col) * 64 + kc * 32 + kg * 8;
      bf16x8 bh = *(const bf16x8*)(Wi_hi + off);
      bf16x8 bl = *(const bf16x8*)(Wi_lo + off);
      gi[t] = MF(ma_hi[kc], bh, gi[t]);
      gi[t] = MF(ma_hi[kc], bl, gi[t]);
      gi[t] = MF(ma_lo[kc], bh, gi[t]);
      bh = *(const bf16x8*)(Wh_hi + off);
      bl = *(const bf16x8*)(Wh_lo + off);
      gh[t] = MF(nf_hi[kc], bh, gh[t]);
      gh[t] = MF(nf_hi[kc], bl, gh[t]);
      gh[t] = MF(nf_lo[kc], bh, gh[t]);
    }
  }

#pragma unroll
  for (int t = 0; t < 4; ++t) {
#pragma unroll
    for (int r = 0; r < 4; ++r) {
      int nn = nrow[r];
      if (nn >= N_NODES_C) continue;
      size_t idx = (size_t)nn * 64 + t * 16 + col;
      float hv = nodeF[idx];
      float rr = sigm(gi[t][r] + gh[t][r]);
      float zz = sigm(gi[t + 4][r] + gh[t + 4][r]);
      float nv = tanhf(gi[t + 8][r] + rr * gh[t + 8][r]);
      nodeF[idx] = (1.f - zz) * nv + zz * hv;
    }
  }
}

// ---------------------------------------------------------------- Set2Set LSTM cell
__global__ void lstm_kernel(const float* __restrict__ qstar,
    const float* __restrict__ w_ih, const float* __restrict__ w_hh,
    const float* __restrict__ b_ih, const float* __restrict__ b_hh,
    float* __restrict__ hl, float* __restrict__ cl) {
  int g = blockIdx.x, o = threadIdx.x;
  __shared__ float qs[128], hs[64];
  qs[o] = qstar[g * 128 + o];
  qs[64 + o] = qstar[g * 128 + 64 + o];
  float hv = hl[g * 64 + o];
  hs[o] = hv;
  __syncthreads();
  float gv[4];
#pragma unroll
  for (int k = 0; k < 4; ++k) {
    float s = b_ih[k * 64 + o] + b_hh[k * 64 + o];
    const float* wi = w_ih + (k * 64 + o) * 128;
    const float* wh = w_hh + (k * 64 + o) * 64;
#pragma unroll 16
    for (int j = 0; j < 128; ++j) s += qs[j] * wi[j];
#pragma unroll 16
    for (int j = 0; j < 64; ++j) s += hs[j] * wh[j];
    gv[k] = s;
  }
  float iv = sigm(gv[0]), fv = sigm(gv[1]), gg = tanhf(gv[2]), ov = sigm(gv[3]);
  float c = fv * cl[g * 64 + o] + iv * gg;
  float hn = ov * tanhf(c);
  cl[g * 64 + o] = c;
  hl[g * 64 + o] = hn;
}

// ---------------------------------------------------------------- segment softmax + readout
__global__ void attn_kernel(const float* __restrict__ out, const float* __restrict__ hl,
    const int* __restrict__ goff, float* __restrict__ ebuf, float* __restrict__ qstar) {
  int g = blockIdx.x, t = threadIdx.x;
  float qv = hl[g * 64 + t];
  int s0 = goff[g], s1 = goff[g + 1];
  float emax = -3.0e38f;
  for (int n = s0; n < s1; ++n) {
    float p = out[n * 64 + t] * qv;
#pragma unroll
    for (int off = 32; off > 0; off >>= 1) p += __shfl_down(p, off);
    float en = __shfl(p, 0);
    if (t == 0) ebuf[n] = en;
    emax = fmaxf(emax, en);
  }
  __syncthreads();
  float lsum = 0.f;
  for (int n = s0 + t; n < s1; n += 64) {
    float ex = __expf(ebuf[n] - emax);
    ebuf[n] = ex;
    lsum += ex;
  }
#pragma unroll
  for (int off = 32; off > 0; off >>= 1) lsum += __shfl_down(lsum, off);
  float denom = __shfl(lsum, 0);
  __syncthreads();
  float r = 0.f;
  for (int n = s0; n < s1; ++n) r += ebuf[n] * out[n * 64 + t];
  if (s1 > s0) r /= denom;
  qstar[g * 128 + t] = qv;
  qstar[g * 128 + 64 + t] = r;
}

// ---------------------------------------------------------------- final linear
__global__ void final_kernel(const float* __restrict__ qstar, const float* __restrict__ lw,
                             const float* __restrict__ lb, float* __restrict__ dout) {
  int b = blockIdx.x * blockDim.x + threadIdx.x;
  if (b >= N_GRAPHS_C) return;
  float s = lb[0];
#pragma unroll 16
  for (int j = 0; j < 128; ++j) s += qstar[b * 128 + j] * lw[j];
  dout[b] = s;
}

// ---------------------------------------------------------------- launch
extern "C" void kernel_launch(void* const* d_in, const int* in_sizes, int n_in,
                              void* d_out, int out_size, void* d_ws, size_t ws_size,
                              hipStream_t stream) {
  const float* x         = (const float*)d_in[0];
  const int*   ei        = (const int*)  d_in[1];
  const float* eattr     = (const float*)d_in[2];
  const int*   batch     = (const int*)  d_in[3];
  const float* lin0_w    = (const float*)d_in[4];
  const float* lin0_b    = (const float*)d_in[5];
  const float* net_w1    = (const float*)d_in[6];
  const float* net_b1    = (const float*)d_in[7];
  const float* net_w2    = (const float*)d_in[8];
  const float* net_b2    = (const float*)d_in[9];
  const float* conv_root = (const float*)d_in[10];
  const float* conv_bias = (const float*)d_in[11];
  const float* gru_w_ih  = (const float*)d_in[12];
  const float* gru_w_hh  = (const float*)d_in[13];
  const float* gru_b_ih  = (const float*)d_in[14];
  const float* gru_b_hh  = (const float*)d_in[15];
  const float* lstm_w_ih = (const float*)d_in[16];
  const float* lstm_w_hh = (const float*)d_in[17];
  const float* lstm_b_ih = (const float*)d_in[18];
  const float* lstm_b_hh = (const float*)d_in[19];
  const float* lin_w     = (const float*)d_in[20];
  const float* lin_b     = (const float*)d_in[21];

  // workspace layout (floats), ~15.3 MB total
  float* ws    = (float*)d_ws;
  float* nodeF = ws;                   // 1,600,000
  float* aggr  = nodeF + 1600000;      // 1,600,000
  float* deg   = aggr + 1600000;       // 25,000
  float* ebuf  = deg + 25000;          // 25,000
  float* hl    = ebuf + 25000;         // 64,000
  float* cl    = hl + 64000;           // 64,000
  float* qstar = cl + 64000;           // 128,000
  int*   goff  = (int*)(qstar + 128000);       // 1,024
  unsigned short* Rt_hi = (unsigned short*)(goff + 1024);  // 4096
  unsigned short* Rt_lo = Rt_hi + 4096;        // 4096
  unsigned short* Wi_hi = Rt_lo + 4096;        // 12288
  unsigned short* Wi_lo = Wi_hi + 12288;       // 12288
  unsigned short* Wh_hi = Wi_lo + 12288;       // 12288
  unsigned short* Wh_lo = Wh_hi + 12288;       // 12288
  _Float16* Wp  = (_Float16*)(Wh_lo + 12288);  // 524,288 (1 MB)
  _Float16* B2p = Wp + 524288;                 // 4,096

  hipMemsetAsync(deg, 0, 25000 * sizeof(float), stream);
  hipMemsetAsync(hl, 0, (64000 + 64000 + 128000) * sizeof(float), stream);  // hl, cl, qstar

  lin0_kernel<<<(N_NODES_C + 3) / 4, 256, 0, stream>>>(x, lin0_w, lin0_b, nodeF);
  deg_kernel<<<(N_EDGES_C + 255) / 256, 256, 0, stream>>>(ei, deg);
  invdeg_kernel<<<(N_NODES_C + 255) / 256, 256, 0, stream>>>(deg);
  goff_kernel<<<(N_GRAPHS_C + 256) / 256, 256, 0, stream>>>(batch, goff);
  prep_kernel<<<48, 256, 0, stream>>>(conv_root, gru_w_ih, gru_w_hh,
                                      Rt_hi, Rt_lo, Wi_hi, Wi_lo, Wh_hi, Wh_lo);
  prep_w2_kernel<<<2048, 256, 0, stream>>>(net_w2, net_b2, Wp, B2p);

  for (int step = 0; step < 3; ++step) {
    hipMemsetAsync(aggr, 0, 1600000 * sizeof(float), stream);
    msg_kernel<<<(N_EDGES_C + EPB - 1) / EPB, 256, 0, stream>>>(
        nodeF, ei, eattr, net_w1, net_b1, Wp, B2p, aggr);
    node_update_kernel<<<(N_NODES_C + 63) / 64, 256, 0, stream>>>(
        aggr, deg, Rt_hi, Rt_lo, Wi_hi, Wi_lo, Wh_hi, Wh_lo,
        conv_bias, gru_b_ih, gru_b_hh, nodeF);
  }

  for (int s = 0; s < 3; ++s) {
    lstm_kernel<<<N_GRAPHS_C, 64, 0, stream>>>(qstar, lstm_w_ih, lstm_w_hh, lstm_b_ih, lstm_b_hh, hl, cl);
    attn_kernel<<<N_GRAPHS_C, 64, 0, stream>>>(nodeF, hl, goff, ebuf, qstar);
  }

  final_kernel<<<(N_GRAPHS_C + 127) / 128, 128, 0, stream>>>(qstar, lin_w, lin_b, (float*)d_out);
}

// Round 5
// 618.259 us; speedup vs baseline: 11.9875x; 1.1868x over previous
//
#include <hip/hip_runtime.h>
#include <math.h>

#define N_NODES_C  25000
#define N_EDGES_C  100000
#define N_GRAPHS_C 1000
#define EPB 128  // edges per block in msg_kernel

typedef __attribute__((ext_vector_type(8))) _Float16 f16x8;
typedef __attribute__((ext_vector_type(4))) float   f32x4;

__device__ __forceinline__ float lrelu(float x) { return x > 0.f ? x : 0.01f * x; }
__device__ __forceinline__ float sigm(float x)  { return 1.f / (1.f + __expf(-x)); }
__device__ __forceinline__ f32x4 MFH(f16x8 a, f16x8 b, f32x4 c) {
  return __builtin_amdgcn_mfma_f32_16x16x32_f16(a, b, c, 0, 0, 0);
}

// ---------------------------------------------------------------- lin0 (LDS-staged weights)
__global__ __launch_bounds__(256) void lin0_kernel(const float* __restrict__ x,
                            const float* __restrict__ w, const float* __restrict__ b,
                            float* __restrict__ nodeF) {
  __shared__ float ws[64 * 15];
  __shared__ float bs[64];
  __shared__ float xr[4][16];
  const int tid = threadIdx.x;
  for (int i = tid; i < 896; i += 256) { int o = i / 14, j = i % 14; ws[o * 15 + j] = w[i]; }
  if (tid < 64) bs[tid] = b[tid];
  const int nl = tid >> 6, o = tid & 63;
  const int n = blockIdx.x * 4 + nl;
  if (o < 14 && n < N_NODES_C) xr[nl][o] = x[n * 14 + o];
  __syncthreads();
  if (n < N_NODES_C) {
    float s = bs[o];
#pragma unroll
    for (int j = 0; j < 14; ++j) s += xr[nl][j] * ws[o * 15 + j];
    nodeF[n * 64 + o] = lrelu(s);
  }
}

// ---------------------------------------------------------------- degree
__global__ void deg_kernel(const int* __restrict__ ei, float* __restrict__ deg) {
  int e = blockIdx.x * blockDim.x + threadIdx.x;
  if (e < N_EDGES_C) atomicAdd(&deg[ei[N_EDGES_C + e]], 1.f);
}

__global__ void invdeg_kernel(float* __restrict__ deg) {
  int n = blockIdx.x * blockDim.x + threadIdx.x;
  if (n < N_NODES_C) { float v = deg[n]; deg[n] = v > 0.f ? 1.f / v : 0.f; }
}

// graph offsets via binary search over sorted batch
__global__ void goff_kernel(const int* __restrict__ batch, int* __restrict__ goff) {
  int g = blockIdx.x * blockDim.x + threadIdx.x;
  if (g > N_GRAPHS_C) return;
  int lo = 0, hi = N_NODES_C;
  while (lo < hi) { int mid = (lo + hi) >> 1; if (batch[mid] < g) lo = mid + 1; else hi = mid; }
  goff[g] = lo;
}

// ---------------------------------------------------------------- GRU weight prep (fp16 frag-major)
// frag(t,kc) element (lane,j): o=t*16+(lane&15), d=kc*32+(lane>>4)*8+j
__global__ void prep_gru_kernel(const float* __restrict__ conv_root,
                                const float* __restrict__ w_ih, const float* __restrict__ w_hh,
                                _Float16* __restrict__ Rtp,
                                _Float16* __restrict__ Wip, _Float16* __restrict__ Whp) {
  int i = blockIdx.x * 256 + threadIdx.x;
  if (i < 12288) {
    int j = i & 7, lane = (i >> 3) & 63, kc = (i >> 9) & 1, t = i >> 10;
    int o = t * 16 + (lane & 15), d = kc * 32 + (lane >> 4) * 8 + j;
    if (i < 4096) Rtp[i] = (_Float16)conv_root[d * 64 + o];  // B[o,d] = root[d,o]
    Wip[i] = (_Float16)w_ih[o * 64 + d];
    Whp[i] = (_Float16)w_hh[o * 64 + d];
  }
}

// ---------------------------------------------------------------- W2 prep: frag-major fp16 image
// Wp[i]: i = ((((d*2+oh)*2+p)*4 + q)*64 + lane)*8 + j ; q = kci*2+ob
//   o = oh*32+ob*16+(lane&15), h = (p*2+kci)*32+(lane>>4)*8+j, value = W2[(d*64+o)*128+h]
// B2p[i]: i = (((oh*2+ob)*2+kc2)*64+lane)*8+j ; o as above, d = kc2*32+(lane>>4)*8+j
__global__ __launch_bounds__(256) void prep_w2_kernel(
    const float* __restrict__ net_w2, const float* __restrict__ net_b2,
    _Float16* __restrict__ Wp, _Float16* __restrict__ B2p) {
  int i = blockIdx.x * 256 + threadIdx.x;  // < 524288
  {
    int j = i & 7, lane = (i >> 3) & 63, q = (i >> 9) & 3, p = (i >> 11) & 1;
    int oh = (i >> 12) & 1, d = i >> 13;
    int kci = q >> 1, ob = q & 1;
    int col = lane & 15, kg = lane >> 4;
    int o = oh * 32 + ob * 16 + col, h = (p * 2 + kci) * 32 + kg * 8 + j;
    Wp[i] = (_Float16)net_w2[((size_t)d * 64 + o) * 128 + h];
  }
  if (i < 4096) {
    int j = i & 7, lane = (i >> 3) & 63, kc2 = (i >> 9) & 1, ob = (i >> 10) & 1, oh = (i >> 11) & 1;
    int col = lane & 15, kg = lane >> 4;
    int o = oh * 32 + ob * 16 + col, d = kc2 * 32 + kg * 8 + j;
    B2p[i] = (_Float16)net_b2[d * 64 + o];
  }
}

// ---------------------------------------------------------------- NNConv message + scatter
// msg = U @ W'^T + x @ B2,  U[e,d*128+h] = x[e,d]*A[e,h]  (fp16 in / fp32 acc)
// 128 edges/block, 4 waves (64e x 32o each). A computed per-lane into regs (step-invariant
// edge MLP, W1 in LDS). kc split into 2 passes -> only 8 A-frags live. LDS 34.5 KB.
__global__ __launch_bounds__(256, 3) void msg_kernel(
    const float* __restrict__ nodef,     // [N,64]
    const int*   __restrict__ ei,        // [2,E]
    const float* __restrict__ eattr,     // [E,4]
    const float* __restrict__ net_w1,    // [128,4]
    const float* __restrict__ net_b1,    // [128]
    const _Float16* __restrict__ Wp,     // frag-major W2 fp16 (1 MB)
    const _Float16* __restrict__ B2p,    // frag-major b2 fp16 (8 KB)
    float* __restrict__ aggr)            // [N,64]
{
  __shared__ _Float16 xs[64 * EPB];    // 16 KB  xs[d][e]
  __shared__ _Float16 xsT[EPB * 64];   // 16 KB  xsT[e][d ^ ((e&7)<<3)]
  __shared__ float    w1s[128 * 5];    // 2.5 KB (w0..w3, b1) per hidden unit

  const int tid = threadIdx.x;
  const int e0 = blockIdx.x * EPB;

  // ---- stage W1+b1
  if (tid < 128) {
    float4 wv = *(const float4*)(net_w1 + tid * 4);
    w1s[tid * 5 + 0] = wv.x; w1s[tid * 5 + 1] = wv.y;
    w1s[tid * 5 + 2] = wv.z; w1s[tid * 5 + 3] = wv.w;
    w1s[tid * 5 + 4] = net_b1[tid];
  }
  // ---- stage x: xs[d][e] scalar + xsT[e][d] frag (fp16), 2 threads/edge
  {
    const int e = tid >> 1, dh = (tid & 1) * 32;
    int ge = e0 + e;
    const int esw = (e & 7) << 3;
#pragma unroll
    for (int jb = 0; jb < 4; ++jb) {
      int d = dh + jb * 8;
      float4 v0, v1;
      if (ge < N_EDGES_C) {
        const float4* nf4 = (const float4*)(nodef + (size_t)ei[ge] * 64 + d);
        v0 = nf4[0]; v1 = nf4[1];
      } else {
        v0 = make_float4(0.f, 0.f, 0.f, 0.f); v1 = v0;
      }
      f16x8 pk;
      pk[0] = (_Float16)v0.x; pk[1] = (_Float16)v0.y; pk[2] = (_Float16)v0.z; pk[3] = (_Float16)v0.w;
      pk[4] = (_Float16)v1.x; pk[5] = (_Float16)v1.y; pk[6] = (_Float16)v1.z; pk[7] = (_Float16)v1.w;
      *(f16x8*)&xsT[e * 64 + (d ^ esw)] = pk;
#pragma unroll
      for (int j = 0; j < 8; ++j) xs[(d + j) * EPB + e] = pk[j];
    }
  }

  const int lane = tid & 63, wv = tid >> 6;
  const int e0w = (wv & 1) * 64;       // wave edge half
  const int oh  = wv >> 1;             // wave output half (32 cols)
  const int col = lane & 15;
  const int kg  = lane >> 4;
  const int swz = (col & 7) << 3;

  __syncthreads();  // staging done; rest of kernel is LDS read-only

  // ---- acc init: x @ B2 (16 MFMA)
  f32x4 acc[4][2];
#pragma unroll
  for (int eb = 0; eb < 4; ++eb) { acc[eb][0] = 0.f; acc[eb][1] = 0.f; }
#pragma unroll
  for (int ob = 0; ob < 2; ++ob)
#pragma unroll
    for (int kc2 = 0; kc2 < 2; ++kc2) {
      f16x8 b2f = *(const f16x8*)(B2p + oh * 2048 + ob * 1024 + kc2 * 512 + lane * 8);
#pragma unroll
      for (int eb = 0; eb < 4; ++eb) {
        f16x8 xf = *(const f16x8*)&xsT[(e0w + eb * 16 + col) * 64 + ((kc2 * 32 + kg * 8) ^ swz)];
        acc[eb][ob] = MFH(xf, b2f, acc[eb][ob]);
      }
    }

  // ---- 2 passes over kc-halves; per pass: build 8 A-frags in regs, then d-loop
  const _Float16* wp_base = Wp + oh * 4096 + lane * 8;  // + p*2048 + d*8192 + q*512
#pragma unroll 1
  for (int p = 0; p < 2; ++p) {
    // A-frags: A[e][h] = lrelu(eattr[e] . w1[h] + b1[h]), h = (p*2+kci)*32 + kg*8 + j
    f16x8 Af[4][2];
    {
      float4 at[4];
#pragma unroll
      for (int eb = 0; eb < 4; ++eb) {
        int ge = e0 + e0w + eb * 16 + col;
        at[eb] = (ge < N_EDGES_C) ? *(const float4*)(eattr + (size_t)ge * 4)
                                  : make_float4(0.f, 0.f, 0.f, 0.f);
      }
#pragma unroll
      for (int kci = 0; kci < 2; ++kci) {
        float4 wr[8]; float wb[8];
#pragma unroll
        for (int j = 0; j < 8; ++j) {
          int hq = (p * 2 + kci) * 32 + kg * 8 + j;
          wr[j] = *(const float4*)&w1s[hq * 5];
          wb[j] = w1s[hq * 5 + 4];
        }
#pragma unroll
        for (int eb = 0; eb < 4; ++eb) {
          f16x8 F;
#pragma unroll
          for (int j = 0; j < 8; ++j) {
            float a = wb[j] + at[eb].x * wr[j].x + at[eb].y * wr[j].y
                            + at[eb].z * wr[j].z + at[eb].w * wr[j].w;
            F[j] = (_Float16)lrelu(a);
          }
          Af[eb][kci] = F;
        }
      }
    }

    const _Float16* wp_p = wp_base + p * 2048;
    f16x8 B0[4], B1[4];
#define LOADB(BUF, dd)                                                   \
  {                                                                      \
    const _Float16* b_ = wp_p + (size_t)(dd) * 8192;                     \
    BUF[0] = *(const f16x8*)(b_);                                        \
    BUF[1] = *(const f16x8*)(b_ + 512);                                  \
    BUF[2] = *(const f16x8*)(b_ + 1024);                                 \
    BUF[3] = *(const f16x8*)(b_ + 1536);                                 \
  }
#define SLAB(BUF, dd)                                                    \
  {                                                                      \
    _Pragma("unroll")                                                    \
    for (int eb = 0; eb < 4; ++eb) {                                     \
      unsigned int xu = *(const unsigned short*)&xs[(dd) * EPB + e0w + eb * 16 + col]; \
      unsigned int xr_ = (xu << 16) | xu;                                \
      union { unsigned int u[4]; f16x8 v; } X;                           \
      X.u[0] = xr_; X.u[1] = xr_; X.u[2] = xr_; X.u[3] = xr_;            \
      _Pragma("unroll")                                                  \
      for (int kci = 0; kci < 2; ++kci) {                                \
        f16x8 U = Af[eb][kci] * X.v;                                     \
        acc[eb][0] = MFH(U, BUF[kci * 2 + 0], acc[eb][0]);               \
        acc[eb][1] = MFH(U, BUF[kci * 2 + 1], acc[eb][1]);               \
      }                                                                  \
    }                                                                    \
  }
    LOADB(B0, 0);
#pragma unroll 1
    for (int d = 0; d < 64; d += 2) {
      LOADB(B1, d + 1);
      SLAB(B0, d);
      if (d + 2 < 64) LOADB(B0, d + 2);
      SLAB(B1, d + 1);
    }
#undef LOADB
#undef SLAB
  }

  // ---- scatter-add into aggr[dst]
  const int o0w = oh * 32;
#pragma unroll
  for (int eb = 0; eb < 4; ++eb) {
#pragma unroll
    for (int r = 0; r < 4; ++r) {
      int e = e0w + eb * 16 + kg * 4 + r;
      int ge = e0 + e;
      if (ge < N_EDGES_C) {
        int dn = ei[N_EDGES_C + ge];
        atomicAdd(&aggr[(size_t)dn * 64 + o0w + col],      acc[eb][0][r]);
        atomicAdd(&aggr[(size_t)dn * 64 + o0w + 16 + col], acc[eb][1][r]);
      }
    }
  }
}

// ---------------------------------------------------------------- root matmul + GRU (fp16 MFMA)
// Block: 64 nodes, 4 waves x 16 nodes. Zeroes aggr in place after reading.
__global__ __launch_bounds__(256) void node_update_kernel(
    float* __restrict__ aggr, const float* __restrict__ invdeg,
    const _Float16* __restrict__ Rtp, const _Float16* __restrict__ Wip,
    const _Float16* __restrict__ Whp,
    const float* __restrict__ conv_bias,
    const float* __restrict__ b_ih, const float* __restrict__ b_hh,
    float* __restrict__ nodeF)
{
  __shared__ _Float16 ms[4][16 * 64];  // per-wave m tile, swizzled (8 KB)

  const int tid = threadIdx.x, lane = tid & 63, wv = tid >> 6;
  const int col = lane & 15, kg = lane >> 4;
  const int nwb = blockIdx.x * 64 + wv * 16;

  int arow = nwb + col; if (arow >= N_NODES_C) arow = N_NODES_C - 1;
  f16x8 nf[2];
#pragma unroll
  for (int kc = 0; kc < 2; ++kc) {
    f32x4 v0 = *(const f32x4*)(nodeF + (size_t)arow * 64 + kc * 32 + kg * 8);
    f32x4 v1 = *(const f32x4*)(nodeF + (size_t)arow * 64 + kc * 32 + kg * 8 + 4);
    f16x8 F;
#pragma unroll
    for (int j = 0; j < 4; ++j) { F[j] = (_Float16)v0[j]; F[4 + j] = (_Float16)v1[j]; }
    nf[kc] = F;
  }

  // ---- Phase 1: root = h @ Rt^T + conv_bias (8 MFMA)
  f32x4 racc[4];
#pragma unroll
  for (int t = 0; t < 4; ++t) racc[t] = conv_bias[t * 16 + col];
#pragma unroll
  for (int t = 0; t < 4; ++t)
#pragma unroll
    for (int kc = 0; kc < 2; ++kc)
      racc[t] = MFH(nf[kc], *(const f16x8*)(Rtp + t * 1024 + kc * 512 + lane * 8), racc[t]);

  // ---- Epilogue 1: m = lrelu(aggr*invdeg + racc); aggr <- 0; m -> LDS (fp16, swizzled)
  float invd[4]; int nrow[4];
#pragma unroll
  for (int r = 0; r < 4; ++r) {
    int nn = nwb + kg * 4 + r; nrow[r] = nn;
    invd[r] = (nn < N_NODES_C) ? invdeg[nn] : 0.f;
  }
#pragma unroll
  for (int t = 0; t < 4; ++t) {
#pragma unroll
    for (int r = 0; r < 4; ++r) {
      int nn = nrow[r];
      float ag = 0.f;
      if (nn < N_NODES_C) {
        size_t idx = (size_t)nn * 64 + t * 16 + col;
        ag = aggr[idx];
        aggr[idx] = 0.f;  // re-zero for next msg step / next replay
      }
      float mval = lrelu(ag * invd[r] + racc[t][r]);
      int nl = kg * 4 + r;
      int dsw = (t * 16 + col) ^ ((nl & 7) << 3);
      ms[wv][nl * 64 + dsw] = (_Float16)mval;
    }
  }
  __syncthreads();

  f16x8 ma[2];
#pragma unroll
  for (int kc = 0; kc < 2; ++kc)
    ma[kc] = *(const f16x8*)&ms[wv][col * 64 + ((kc * 32 + kg * 8) ^ ((col & 7) << 3))];

  // ---- Phase 2: gi = m @ Wi^T + b_ih ; gh = h @ Wh^T + b_hh  (48 MFMA)
  f32x4 gi[12], gh[12];
#pragma unroll
  for (int t = 0; t < 12; ++t) { gi[t] = b_ih[t * 16 + col]; gh[t] = b_hh[t * 16 + col]; }
#pragma unroll
  for (int t = 0; t < 12; ++t)
#pragma unroll
    for (int kc = 0; kc < 2; ++kc) {
      gi[t] = MFH(ma[kc], *(const f16x8*)(Wip + t * 1024 + kc * 512 + lane * 8), gi[t]);
      gh[t] = MFH(nf[kc], *(const f16x8*)(Whp + t * 1024 + kc * 512 + lane * 8), gh[t]);
    }

  // ---- Epilogue 2: GRU combine, h -> nodeF
#pragma unroll
  for (int t = 0; t < 4; ++t) {
#pragma unroll
    for (int r = 0; r < 4; ++r) {
      int nn = nrow[r];
      if (nn >= N_NODES_C) continue;
      size_t idx = (size_t)nn * 64 + t * 16 + col;
      float hv = nodeF[idx];
      float rr = sigm(gi[t][r] + gh[t][r]);
      float zz = sigm(gi[t + 4][r] + gh[t + 4][r]);
      float nv = tanhf(gi[t + 8][r] + rr * gh[t + 8][r]);
      nodeF[idx] = (1.f - zz) * nv + zz * hv;
    }
  }
}

// ---------------------------------------------------------------- fused Set2Set (3 steps) + final linear
// One block per graph; hl/cl per-thread, qstar in LDS. ebuf is global per-node scratch.
__global__ __launch_bounds__(64) void set2set_kernel(
    const float* __restrict__ nodeF, const int* __restrict__ goff,
    const float* __restrict__ w_ih, const float* __restrict__ w_hh,
    const float* __restrict__ b_ih, const float* __restrict__ b_hh,
    const float* __restrict__ lw, const float* __restrict__ lb,
    float* __restrict__ ebuf, float* __restrict__ dout)
{
  const int g = blockIdx.x, t = threadIdx.x;
  __shared__ float qs[128], hs[64];
  float hl = 0.f, cl = 0.f;
  qs[t] = 0.f; qs[64 + t] = 0.f;
  const int s0 = goff[g], s1 = goff[g + 1];

  for (int step = 0; step < 3; ++step) {
    hs[t] = hl;
    __syncthreads();
    float gv[4];
#pragma unroll
    for (int k = 0; k < 4; ++k) {
      float s = b_ih[k * 64 + t] + b_hh[k * 64 + t];
      const float4* wi4 = (const float4*)(w_ih + (k * 64 + t) * 128);
#pragma unroll 8
      for (int j = 0; j < 32; ++j) {
        float4 w = wi4[j];
        s += qs[4 * j] * w.x + qs[4 * j + 1] * w.y + qs[4 * j + 2] * w.z + qs[4 * j + 3] * w.w;
      }
      const float4* wh4 = (const float4*)(w_hh + (k * 64 + t) * 64);
#pragma unroll 8
      for (int j = 0; j < 16; ++j) {
        float4 w = wh4[j];
        s += hs[4 * j] * w.x + hs[4 * j + 1] * w.y + hs[4 * j + 2] * w.z + hs[4 * j + 3] * w.w;
      }
      gv[k] = s;
    }
    cl = sigm(gv[1]) * cl + sigm(gv[0]) * tanhf(gv[2]);
    hl = sigm(gv[3]) * tanhf(cl);
    const float qv = hl;

    // segment softmax attention
    float emax = -3.0e38f;
    for (int n = s0; n < s1; ++n) {
      float p = nodeF[n * 64 + t] * qv;
#pragma unroll
      for (int off = 32; off > 0; off >>= 1) p += __shfl_down(p, off);
      float en = __shfl(p, 0);
      if (t == 0) ebuf[n] = en;
      emax = fmaxf(emax, en);
    }
    __syncthreads();  // drain ebuf writes
    float lsum = 0.f;
    for (int n = s0 + t; n < s1; n += 64) {
      float ex = __expf(ebuf[n] - emax);
      ebuf[n] = ex;
      lsum += ex;
    }
#pragma unroll
    for (int off = 32; off > 0; off >>= 1) lsum += __shfl_down(lsum, off);
    float denom = __shfl(lsum, 0);
    __syncthreads();  // drain exp writes
    float r = 0.f;
    for (int n = s0; n < s1; ++n) r += ebuf[n] * nodeF[n * 64 + t];
    if (s1 > s0) r /= denom;
    qs[t] = qv; qs[64 + t] = r;  // visible after next loop-top barrier
  }
  __syncthreads();
  float s = qs[t] * lw[t] + qs[64 + t] * lw[64 + t];
#pragma unroll
  for (int off = 32; off > 0; off >>= 1) s += __shfl_down(s, off);
  if (t == 0) dout[g] = s + lb[0];
}

// ---------------------------------------------------------------- launch
extern "C" void kernel_launch(void* const* d_in, const int* in_sizes, int n_in,
                              void* d_out, int out_size, void* d_ws, size_t ws_size,
                              hipStream_t stream) {
  const float* x         = (const float*)d_in[0];
  const int*   ei        = (const int*)  d_in[1];
  const float* eattr     = (const float*)d_in[2];
  const int*   batch     = (const int*)  d_in[3];
  const float* lin0_w    = (const float*)d_in[4];
  const float* lin0_b    = (const float*)d_in[5];
  const float* net_w1    = (const float*)d_in[6];
  const float* net_b1    = (const float*)d_in[7];
  const float* net_w2    = (const float*)d_in[8];
  const float* net_b2    = (const float*)d_in[9];
  const float* conv_root = (const float*)d_in[10];
  const float* conv_bias = (const float*)d_in[11];
  const float* gru_w_ih  = (const float*)d_in[12];
  const float* gru_w_hh  = (const float*)d_in[13];
  const float* gru_b_ih  = (const float*)d_in[14];
  const float* gru_b_hh  = (const float*)d_in[15];
  const float* lstm_w_ih = (const float*)d_in[16];
  const float* lstm_w_hh = (const float*)d_in[17];
  const float* lstm_b_ih = (const float*)d_in[18];
  const float* lstm_b_hh = (const float*)d_in[19];
  const float* lin_w     = (const float*)d_in[20];
  const float* lin_b     = (const float*)d_in[21];

  // workspace layout (~13.1 MB)
  float* ws    = (float*)d_ws;
  float* nodeF = ws;                         // 1,600,000 f
  float* aggr  = nodeF + 1600000;            // 1,600,000 f
  float* deg   = aggr + 1600000;             //    25,000 f
  float* ebuf  = deg + 25000;                //    25,000 f
  int*   goff  = (int*)(ebuf + 25000);       //     1,024 i
  _Float16* Rtp = (_Float16*)(goff + 1024);  //     4,096 h
  _Float16* Wip = Rtp + 4096;                //    12,288 h
  _Float16* Whp = Wip + 12288;               //    12,288 h
  _Float16* Wp  = Whp + 12288;               //   524,288 h
  _Float16* B2p = Wp + 524288;               //     4,096 h

  hipMemsetAsync(deg, 0, 25000 * sizeof(float), stream);
  hipMemsetAsync(aggr, 0, 1600000 * sizeof(float), stream);  // node_update re-zeroes thereafter

  lin0_kernel<<<(N_NODES_C + 3) / 4, 256, 0, stream>>>(x, lin0_w, lin0_b, nodeF);
  deg_kernel<<<(N_EDGES_C + 255) / 256, 256, 0, stream>>>(ei, deg);
  invdeg_kernel<<<(N_NODES_C + 255) / 256, 256, 0, stream>>>(deg);
  goff_kernel<<<(N_GRAPHS_C + 256) / 256, 256, 0, stream>>>(batch, goff);
  prep_gru_kernel<<<48, 256, 0, stream>>>(conv_root, gru_w_ih, gru_w_hh, Rtp, Wip, Whp);
  prep_w2_kernel<<<2048, 256, 0, stream>>>(net_w2, net_b2, Wp, B2p);

  for (int step = 0; step < 3; ++step) {
    msg_kernel<<<(N_EDGES_C + EPB - 1) / EPB, 256, 0, stream>>>(
        nodeF, ei, eattr, net_w1, net_b1, Wp, B2p, aggr);
    node_update_kernel<<<(N_NODES_C + 63) / 64, 256, 0, stream>>>(
        aggr, deg, Rtp, Wip, Whp, conv_bias, gru_b_ih, gru_b_hh, nodeF);
  }

  set2set_kernel<<<N_GRAPHS_C, 64, 0, stream>>>(
      nodeF, goff, lstm_w_ih, lstm_w_hh, lstm_b_ih, lstm_b_hh, lin_w, lin_b, ebuf, (float*)d_out);
}

// Round 6
// 602.203 us; speedup vs baseline: 12.3071x; 1.0267x over previous
//
#include <hip/hip_runtime.h>
#include <math.h>

#define N_NODES_C  25000
#define N_EDGES_C  100000
#define N_GRAPHS_C 1000
#define EPB 128  // edges per block in msg_kernel

typedef __attribute__((ext_vector_type(8))) _Float16 f16x8;
typedef __attribute__((ext_vector_type(2))) _Float16 f16x2;
typedef __attribute__((ext_vector_type(4))) float   f32x4;

__device__ __forceinline__ float lrelu(float x) { return x > 0.f ? x : 0.01f * x; }
__device__ __forceinline__ float sigm(float x)  { return 1.f / (1.f + __expf(-x)); }
__device__ __forceinline__ f32x4 MFH(f16x8 a, f16x8 b, f32x4 c) {
  return __builtin_amdgcn_mfma_f32_16x16x32_f16(a, b, c, 0, 0, 0);
}

// ---------------------------------------------------------------- lin0 (LDS-staged weights)
__global__ __launch_bounds__(256) void lin0_kernel(const float* __restrict__ x,
                            const float* __restrict__ w, const float* __restrict__ b,
                            float* __restrict__ nodeF) {
  __shared__ float ws[64 * 15];
  __shared__ float bs[64];
  __shared__ float xr[4][16];
  const int tid = threadIdx.x;
  for (int i = tid; i < 896; i += 256) { int o = i / 14, j = i % 14; ws[o * 15 + j] = w[i]; }
  if (tid < 64) bs[tid] = b[tid];
  const int nl = tid >> 6, o = tid & 63;
  const int n = blockIdx.x * 4 + nl;
  if (o < 14 && n < N_NODES_C) xr[nl][o] = x[n * 14 + o];
  __syncthreads();
  if (n < N_NODES_C) {
    float s = bs[o];
#pragma unroll
    for (int j = 0; j < 14; ++j) s += xr[nl][j] * ws[o * 15 + j];
    nodeF[n * 64 + o] = lrelu(s);
  }
}

// ---------------------------------------------------------------- degree
__global__ void deg_kernel(const int* __restrict__ ei, float* __restrict__ deg) {
  int e = blockIdx.x * blockDim.x + threadIdx.x;
  if (e < N_EDGES_C) atomicAdd(&deg[ei[N_EDGES_C + e]], 1.f);
}

__global__ void invdeg_kernel(float* __restrict__ deg) {
  int n = blockIdx.x * blockDim.x + threadIdx.x;
  if (n < N_NODES_C) { float v = deg[n]; deg[n] = v > 0.f ? 1.f / v : 0.f; }
}

// graph offsets via binary search over sorted batch
__global__ void goff_kernel(const int* __restrict__ batch, int* __restrict__ goff) {
  int g = blockIdx.x * blockDim.x + threadIdx.x;
  if (g > N_GRAPHS_C) return;
  int lo = 0, hi = N_NODES_C;
  while (lo < hi) { int mid = (lo + hi) >> 1; if (batch[mid] < g) lo = mid + 1; else hi = mid; }
  goff[g] = lo;
}

// ---------------------------------------------------------------- GRU weight prep (fp16 frag-major)
// frag(t,kc) element (lane,j): o=t*16+(lane&15), d=kc*32+(lane>>4)*8+j
__global__ void prep_gru_kernel(const float* __restrict__ conv_root,
                                const float* __restrict__ w_ih, const float* __restrict__ w_hh,
                                _Float16* __restrict__ Rtp,
                                _Float16* __restrict__ Wip, _Float16* __restrict__ Whp) {
  int i = blockIdx.x * 256 + threadIdx.x;
  if (i < 12288) {
    int j = i & 7, lane = (i >> 3) & 63, kc = (i >> 9) & 1, t = i >> 10;
    int o = t * 16 + (lane & 15), d = kc * 32 + (lane >> 4) * 8 + j;
    if (i < 4096) Rtp[i] = (_Float16)conv_root[d * 64 + o];  // B[o,d] = root[d,o]
    Wip[i] = (_Float16)w_ih[o * 64 + d];
    Whp[i] = (_Float16)w_hh[o * 64 + d];
  }
}

// ---------------------------------------------------------------- W2 prep: frag-major fp16 image
// Wp[i]: i = ((((d*2+oh)*2+p)*4 + q)*64 + lane)*8 + j ; q = kci*2+ob
//   o = oh*32+ob*16+(lane&15), h = (p*2+kci)*32+(lane>>4)*8+j, value = W2[(d*64+o)*128+h]
// B2p[i]: i = (((oh*2+ob)*2+kc2)*64+lane)*8+j ; o as above, d = kc2*32+(lane>>4)*8+j
__global__ __launch_bounds__(256) void prep_w2_kernel(
    const float* __restrict__ net_w2, const float* __restrict__ net_b2,
    _Float16* __restrict__ Wp, _Float16* __restrict__ B2p) {
  int i = blockIdx.x * 256 + threadIdx.x;  // < 524288
  {
    int j = i & 7, lane = (i >> 3) & 63, q = (i >> 9) & 3, p = (i >> 11) & 1;
    int oh = (i >> 12) & 1, d = i >> 13;
    int kci = q >> 1, ob = q & 1;
    int col = lane & 15, kg = lane >> 4;
    int o = oh * 32 + ob * 16 + col, h = (p * 2 + kci) * 32 + kg * 8 + j;
    Wp[i] = (_Float16)net_w2[((size_t)d * 64 + o) * 128 + h];
  }
  if (i < 4096) {
    int j = i & 7, lane = (i >> 3) & 63, kc2 = (i >> 9) & 1, ob = (i >> 10) & 1, oh = (i >> 11) & 1;
    int col = lane & 15, kg = lane >> 4;
    int o = oh * 32 + ob * 16 + col, d = kc2 * 32 + kg * 8 + j;
    B2p[i] = (_Float16)net_b2[d * 64 + o];
  }
}

// ---------------------------------------------------------------- NNConv message + scatter
// msg = U @ W'^T + x @ B2,  U[e,d*128+h] = x[e,d]*A[e,h]  (fp16 in / fp32 acc)
// 128 edges/block, 4 waves (64e x 32o each). A computed per-lane into regs.
// x read as f16x8 vectors from swizzled xsT; per-d splat via v_perm_b32.
// LDS 18.5 KB, 4 blocks/CU -> all 782 blocks co-resident (no tail).
__global__ __launch_bounds__(256, 4) void msg_kernel(
    const float* __restrict__ nodef,     // [N,64]
    const int*   __restrict__ ei,        // [2,E]
    const float* __restrict__ eattr,     // [E,4]
    const float* __restrict__ net_w1,    // [128,4]
    const float* __restrict__ net_b1,    // [128]
    const _Float16* __restrict__ Wp,     // frag-major W2 fp16 (1 MB)
    const _Float16* __restrict__ B2p,    // frag-major b2 fp16 (8 KB)
    float* __restrict__ aggr)            // [N,64]
{
  __shared__ _Float16 xsT[EPB * 64];   // 16 KB  xsT[e][d ^ ((e&7)<<3)]
  __shared__ float    w1s[128 * 5];    // 2.5 KB (w0..w3, b1) per hidden unit

  const int tid = threadIdx.x;
  const int e0 = blockIdx.x * EPB;

  // ---- stage W1+b1
  if (tid < 128) {
    float4 wv = *(const float4*)(net_w1 + tid * 4);
    w1s[tid * 5 + 0] = wv.x; w1s[tid * 5 + 1] = wv.y;
    w1s[tid * 5 + 2] = wv.z; w1s[tid * 5 + 3] = wv.w;
    w1s[tid * 5 + 4] = net_b1[tid];
  }
  // ---- stage x: xsT[e][d] (fp16, swizzled), 2 threads/edge
  {
    const int e = tid >> 1, dh = (tid & 1) * 32;
    int ge = e0 + e;
    const int esw = (e & 7) << 3;
#pragma unroll
    for (int jb = 0; jb < 4; ++jb) {
      int d = dh + jb * 8;
      float4 v0, v1;
      if (ge < N_EDGES_C) {
        const float4* nf4 = (const float4*)(nodef + (size_t)ei[ge] * 64 + d);
        v0 = nf4[0]; v1 = nf4[1];
      } else {
        v0 = make_float4(0.f, 0.f, 0.f, 0.f); v1 = v0;
      }
      f16x8 pk;
      pk[0] = (_Float16)v0.x; pk[1] = (_Float16)v0.y; pk[2] = (_Float16)v0.z; pk[3] = (_Float16)v0.w;
      pk[4] = (_Float16)v1.x; pk[5] = (_Float16)v1.y; pk[6] = (_Float16)v1.z; pk[7] = (_Float16)v1.w;
      *(f16x8*)&xsT[e * 64 + (d ^ esw)] = pk;
    }
  }

  const int lane = tid & 63, wv = tid >> 6;
  const int e0w = (wv & 1) * 64;       // wave edge half
  const int oh  = wv >> 1;             // wave output half (32 cols)
  const int col = lane & 15;
  const int kg  = lane >> 4;
  const int swz = (col & 7) << 3;

  __syncthreads();  // staging done; rest of kernel is LDS read-only

  // ---- acc init: x @ B2 (16 MFMA)
  f32x4 acc[4][2];
#pragma unroll
  for (int eb = 0; eb < 4; ++eb) { acc[eb][0] = 0.f; acc[eb][1] = 0.f; }
#pragma unroll
  for (int ob = 0; ob < 2; ++ob)
#pragma unroll
    for (int kc2 = 0; kc2 < 2; ++kc2) {
      f16x8 b2f = *(const f16x8*)(B2p + oh * 2048 + ob * 1024 + kc2 * 512 + lane * 8);
#pragma unroll
      for (int eb = 0; eb < 4; ++eb) {
        f16x8 xf = *(const f16x8*)&xsT[(e0w + eb * 16 + col) * 64 + ((kc2 * 32 + kg * 8) ^ swz)];
        acc[eb][ob] = MFH(xf, b2f, acc[eb][ob]);
      }
    }

  // ---- 2 passes over kc-halves; per pass: build 8 A-frags in regs, then d-loop
  const _Float16* wp_base = Wp + oh * 4096 + lane * 8;  // + p*2048 + d*8192 + q*512
#pragma unroll 1
  for (int p = 0; p < 2; ++p) {
    // A-frags: A[e][h] = lrelu(eattr[e] . w1[h] + b1[h]), h = (p*2+kci)*32 + kg*8 + j
    f16x8 Af[4][2];
    {
      float4 at[4];
#pragma unroll
      for (int eb = 0; eb < 4; ++eb) {
        int ge = e0 + e0w + eb * 16 + col;
        at[eb] = (ge < N_EDGES_C) ? *(const float4*)(eattr + (size_t)ge * 4)
                                  : make_float4(0.f, 0.f, 0.f, 0.f);
      }
#pragma unroll
      for (int kci = 0; kci < 2; ++kci) {
        float4 wr[8]; float wb[8];
#pragma unroll
        for (int j = 0; j < 8; ++j) {
          int hq = (p * 2 + kci) * 32 + kg * 8 + j;
          wr[j] = *(const float4*)&w1s[hq * 5];
          wb[j] = w1s[hq * 5 + 4];
        }
#pragma unroll
        for (int eb = 0; eb < 4; ++eb) {
          f16x8 F;
#pragma unroll
          for (int j = 0; j < 8; ++j) {
            float a = wb[j] + at[eb].x * wr[j].x + at[eb].y * wr[j].y
                            + at[eb].z * wr[j].z + at[eb].w * wr[j].w;
            F[j] = (_Float16)lrelu(a);
          }
          Af[eb][kci] = F;
        }
      }
    }

    const _Float16* wp_p = wp_base + p * 2048;
    f16x8 Bb[2][4];
#define LOADB(BUF, dd)                                                   \
  {                                                                      \
    const _Float16* b_ = wp_p + (size_t)(dd) * 8192;                     \
    BUF[0] = *(const f16x8*)(b_);                                        \
    BUF[1] = *(const f16x8*)(b_ + 512);                                  \
    BUF[2] = *(const f16x8*)(b_ + 1024);                                 \
    BUF[3] = *(const f16x8*)(b_ + 1536);                                 \
  }
    LOADB(Bb[0], 0);
#pragma unroll 1
    for (int d8 = 0; d8 < 64; d8 += 8) {
      // x vectors for this 8-d group (2-way bank aliasing = free)
      union { f16x8 v; unsigned u[4]; } XV[4];
#pragma unroll
      for (int eb = 0; eb < 4; ++eb)
        XV[eb].v = *(const f16x8*)&xsT[(e0w + eb * 16 + col) * 64 + (d8 ^ swz)];
#pragma unroll
      for (int j = 0; j < 8; ++j) {
        int d = d8 + j;
        if (d < 63) LOADB(Bb[(j + 1) & 1], d + 1);  // prefetch next slab
        const f16x8* B = Bb[j & 1];
#pragma unroll
        for (int eb = 0; eb < 4; ++eb) {
          unsigned dw = XV[eb].u[j >> 1];
          unsigned xd = __builtin_amdgcn_perm(dw, dw, (j & 1) ? 0x03020302u : 0x01000100u);
          f16x2 x2; { union { unsigned u; f16x2 h; } c; c.u = xd; x2 = c.h; }
#pragma unroll
          for (int kci = 0; kci < 2; ++kci) {
            union { f16x8 v; f16x2 p[4]; } af, Uu;
            af.v = Af[eb][kci];
#pragma unroll
            for (int q = 0; q < 4; ++q) Uu.p[q] = af.p[q] * x2;
            acc[eb][0] = MFH(Uu.v, B[kci * 2 + 0], acc[eb][0]);
            acc[eb][1] = MFH(Uu.v, B[kci * 2 + 1], acc[eb][1]);
          }
        }
      }
    }
#undef LOADB
  }

  // ---- scatter-add into aggr[dst]
  const int o0w = oh * 32;
#pragma unroll
  for (int eb = 0; eb < 4; ++eb) {
#pragma unroll
    for (int r = 0; r < 4; ++r) {
      int e = e0w + eb * 16 + kg * 4 + r;
      int ge = e0 + e;
      if (ge < N_EDGES_C) {
        int dn = ei[N_EDGES_C + ge];
        atomicAdd(&aggr[(size_t)dn * 64 + o0w + col],      acc[eb][0][r]);
        atomicAdd(&aggr[(size_t)dn * 64 + o0w + 16 + col], acc[eb][1][r]);
      }
    }
  }
}

// ---------------------------------------------------------------- root matmul + GRU (fp16 MFMA)
// Block: 64 nodes, 4 waves x 16 nodes. Zeroes aggr in place after reading.
__global__ __launch_bounds__(256) void node_update_kernel(
    float* __restrict__ aggr, const float* __restrict__ invdeg,
    const _Float16* __restrict__ Rtp, const _Float16* __restrict__ Wip,
    const _Float16* __restrict__ Whp,
    const float* __restrict__ conv_bias,
    const float* __restrict__ b_ih, const float* __restrict__ b_hh,
    float* __restrict__ nodeF)
{
  __shared__ _Float16 ms[4][16 * 64];  // per-wave m tile, swizzled (8 KB)

  const int tid = threadIdx.x, lane = tid & 63, wv = tid >> 6;
  const int col = lane & 15, kg = lane >> 4;
  const int nwb = blockIdx.x * 64 + wv * 16;

  int arow = nwb + col; if (arow >= N_NODES_C) arow = N_NODES_C - 1;
  f16x8 nf[2];
#pragma unroll
  for (int kc = 0; kc < 2; ++kc) {
    f32x4 v0 = *(const f32x4*)(nodeF + (size_t)arow * 64 + kc * 32 + kg * 8);
    f32x4 v1 = *(const f32x4*)(nodeF + (size_t)arow * 64 + kc * 32 + kg * 8 + 4);
    f16x8 F;
#pragma unroll
    for (int j = 0; j < 4; ++j) { F[j] = (_Float16)v0[j]; F[4 + j] = (_Float16)v1[j]; }
    nf[kc] = F;
  }

  // ---- Phase 1: root = h @ Rt^T + conv_bias (8 MFMA)
  f32x4 racc[4];
#pragma unroll
  for (int t = 0; t < 4; ++t) racc[t] = conv_bias[t * 16 + col];
#pragma unroll
  for (int t = 0; t < 4; ++t)
#pragma unroll
    for (int kc = 0; kc < 2; ++kc)
      racc[t] = MFH(nf[kc], *(const f16x8*)(Rtp + t * 1024 + kc * 512 + lane * 8), racc[t]);

  // ---- Epilogue 1: m = lrelu(aggr*invdeg + racc); aggr <- 0; m -> LDS (fp16, swizzled)
  float invd[4]; int nrow[4];
#pragma unroll
  for (int r = 0; r < 4; ++r) {
    int nn = nwb + kg * 4 + r; nrow[r] = nn;
    invd[r] = (nn < N_NODES_C) ? invdeg[nn] : 0.f;
  }
#pragma unroll
  for (int t = 0; t < 4; ++t) {
#pragma unroll
    for (int r = 0; r < 4; ++r) {
      int nn = nrow[r];
      float ag = 0.f;
      if (nn < N_NODES_C) {
        size_t idx = (size_t)nn * 64 + t * 16 + col;
        ag = aggr[idx];
        aggr[idx] = 0.f;  // re-zero for next msg step / next replay
      }
      float mval = lrelu(ag * invd[r] + racc[t][r]);
      int nl = kg * 4 + r;
      int dsw = (t * 16 + col) ^ ((nl & 7) << 3);
      ms[wv][nl * 64 + dsw] = (_Float16)mval;
    }
  }
  __syncthreads();

  f16x8 ma[2];
#pragma unroll
  for (int kc = 0; kc < 2; ++kc)
    ma[kc] = *(const f16x8*)&ms[wv][col * 64 + ((kc * 32 + kg * 8) ^ ((col & 7) << 3))];

  // ---- Phase 2: gi = m @ Wi^T + b_ih ; gh = h @ Wh^T + b_hh  (48 MFMA)
  f32x4 gi[12], gh[12];
#pragma unroll
  for (int t = 0; t < 12; ++t) { gi[t] = b_ih[t * 16 + col]; gh[t] = b_hh[t * 16 + col]; }
#pragma unroll
  for (int t = 0; t < 12; ++t)
#pragma unroll
    for (int kc = 0; kc < 2; ++kc) {
      gi[t] = MFH(ma[kc], *(const f16x8*)(Wip + t * 1024 + kc * 512 + lane * 8), gi[t]);
      gh[t] = MFH(nf[kc], *(const f16x8*)(Whp + t * 1024 + kc * 512 + lane * 8), gh[t]);
    }

  // ---- Epilogue 2: GRU combine, h -> nodeF
#pragma unroll
  for (int t = 0; t < 4; ++t) {
#pragma unroll
    for (int r = 0; r < 4; ++r) {
      int nn = nrow[r];
      if (nn >= N_NODES_C) continue;
      size_t idx = (size_t)nn * 64 + t * 16 + col;
      float hv = nodeF[idx];
      float rr = sigm(gi[t][r] + gh[t][r]);
      float zz = sigm(gi[t + 4][r] + gh[t + 4][r]);
      float nv = tanhf(gi[t + 8][r] + rr * gh[t + 8][r]);
      nodeF[idx] = (1.f - zz) * nv + zz * hv;
    }
  }
}

// ---------------------------------------------------------------- fused Set2Set (3 steps) + final linear
__global__ __launch_bounds__(64) void set2set_kernel(
    const float* __restrict__ nodeF, const int* __restrict__ goff,
    const float* __restrict__ w_ih, const float* __restrict__ w_hh,
    const float* __restrict__ b_ih, const float* __restrict__ b_hh,
    const float* __restrict__ lw, const float* __restrict__ lb,
    float* __restrict__ ebuf, float* __restrict__ dout)
{
  const int g = blockIdx.x, t = threadIdx.x;
  __shared__ float qs[128], hs[64];
  float hl = 0.f, cl = 0.f;
  qs[t] = 0.f; qs[64 + t] = 0.f;
  const int s0 = goff[g], s1 = goff[g + 1];

  for (int step = 0; step < 3; ++step) {
    hs[t] = hl;
    __syncthreads();
    float gv[4];
#pragma unroll
    for (int k = 0; k < 4; ++k) {
      float s = b_ih[k * 64 + t] + b_hh[k * 64 + t];
      const float4* wi4 = (const float4*)(w_ih + (k * 64 + t) * 128);
#pragma unroll 8
      for (int j = 0; j < 32; ++j) {
        float4 w = wi4[j];
        s += qs[4 * j] * w.x + qs[4 * j + 1] * w.y + qs[4 * j + 2] * w.z + qs[4 * j + 3] * w.w;
      }
      const float4* wh4 = (const float4*)(w_hh + (k * 64 + t) * 64);
#pragma unroll 8
      for (int j = 0; j < 16; ++j) {
        float4 w = wh4[j];
        s += hs[4 * j] * w.x + hs[4 * j + 1] * w.y + hs[4 * j + 2] * w.z + hs[4 * j + 3] * w.w;
      }
      gv[k] = s;
    }
    cl = sigm(gv[1]) * cl + sigm(gv[0]) * tanhf(gv[2]);
    hl = sigm(gv[3]) * tanhf(cl);
    const float qv = hl;

    // segment softmax attention
    float emax = -3.0e38f;
    for (int n = s0; n < s1; ++n) {
      float p = nodeF[n * 64 + t] * qv;
#pragma unroll
      for (int off = 32; off > 0; off >>= 1) p += __shfl_down(p, off);
      float en = __shfl(p, 0);
      if (t == 0) ebuf[n] = en;
      emax = fmaxf(emax, en);
    }
    __syncthreads();  // drain ebuf writes
    float lsum = 0.f;
    for (int n = s0 + t; n < s1; n += 64) {
      float ex = __expf(ebuf[n] - emax);
      ebuf[n] = ex;
      lsum += ex;
    }
#pragma unroll
    for (int off = 32; off > 0; off >>= 1) lsum += __shfl_down(lsum, off);
    float denom = __shfl(lsum, 0);
    __syncthreads();  // drain exp writes
    float r = 0.f;
    for (int n = s0; n < s1; ++n) r += ebuf[n] * nodeF[n * 64 + t];
    if (s1 > s0) r /= denom;
    qs[t] = qv; qs[64 + t] = r;  // visible after next loop-top barrier
  }
  __syncthreads();
  float s = qs[t] * lw[t] + qs[64 + t] * lw[64 + t];
#pragma unroll
  for (int off = 32; off > 0; off >>= 1) s += __shfl_down(s, off);
  if (t == 0) dout[g] = s + lb[0];
}

// ---------------------------------------------------------------- launch
extern "C" void kernel_launch(void* const* d_in, const int* in_sizes, int n_in,
                              void* d_out, int out_size, void* d_ws, size_t ws_size,
                              hipStream_t stream) {
  const float* x         = (const float*)d_in[0];
  const int*   ei        = (const int*)  d_in[1];
  const float* eattr     = (const float*)d_in[2];
  const int*   batch     = (const int*)  d_in[3];
  const float* lin0_w    = (const float*)d_in[4];
  const float* lin0_b    = (const float*)d_in[5];
  const float* net_w1    = (const float*)d_in[6];
  const float* net_b1    = (const float*)d_in[7];
  const float* net_w2    = (const float*)d_in[8];
  const float* net_b2    = (const float*)d_in[9];
  const float* conv_root = (const float*)d_in[10];
  const float* conv_bias = (const float*)d_in[11];
  const float* gru_w_ih  = (const float*)d_in[12];
  const float* gru_w_hh  = (const float*)d_in[13];
  const float* gru_b_ih  = (const float*)d_in[14];
  const float* gru_b_hh  = (const float*)d_in[15];
  const float* lstm_w_ih = (const float*)d_in[16];
  const float* lstm_w_hh = (const float*)d_in[17];
  const float* lstm_b_ih = (const float*)d_in[18];
  const float* lstm_b_hh = (const float*)d_in[19];
  const float* lin_w     = (const float*)d_in[20];
  const float* lin_b     = (const float*)d_in[21];

  // workspace layout (~13.1 MB)
  float* ws    = (float*)d_ws;
  float* nodeF = ws;                         // 1,600,000 f
  float* aggr  = nodeF + 1600000;            // 1,600,000 f
  float* deg   = aggr + 1600000;             //    25,000 f
  float* ebuf  = deg + 25000;                //    25,000 f
  int*   goff  = (int*)(ebuf + 25000);       //     1,024 i
  _Float16* Rtp = (_Float16*)(goff + 1024);  //     4,096 h
  _Float16* Wip = Rtp + 4096;                //    12,288 h
  _Float16* Whp = Wip + 12288;               //    12,288 h
  _Float16* Wp  = Whp + 12288;               //   524,288 h
  _Float16* B2p = Wp + 524288;               //     4,096 h

  hipMemsetAsync(deg, 0, 25000 * sizeof(float), stream);
  hipMemsetAsync(aggr, 0, 1600000 * sizeof(float), stream);  // node_update re-zeroes thereafter

  lin0_kernel<<<(N_NODES_C + 3) / 4, 256, 0, stream>>>(x, lin0_w, lin0_b, nodeF);
  deg_kernel<<<(N_EDGES_C + 255) / 256, 256, 0, stream>>>(ei, deg);
  invdeg_kernel<<<(N_NODES_C + 255) / 256, 256, 0, stream>>>(deg);
  goff_kernel<<<(N_GRAPHS_C + 256) / 256, 256, 0, stream>>>(batch, goff);
  prep_gru_kernel<<<48, 256, 0, stream>>>(conv_root, gru_w_ih, gru_w_hh, Rtp, Wip, Whp);
  prep_w2_kernel<<<2048, 256, 0, stream>>>(net_w2, net_b2, Wp, B2p);

  for (int step = 0; step < 3; ++step) {
    msg_kernel<<<(N_EDGES_C + EPB - 1) / EPB, 256, 0, stream>>>(
        nodeF, ei, eattr, net_w1, net_b1, Wp, B2p, aggr);
    node_update_kernel<<<(N_NODES_C + 63) / 64, 256, 0, stream>>>(
        aggr, deg, Rtp, Wip, Whp, conv_bias, gru_b_ih, gru_b_hh, nodeF);
  }

  set2set_kernel<<<N_GRAPHS_C, 64, 0, stream>>>(
      nodeF, goff, lstm_w_ih, lstm_w_hh, lstm_b_ih, lstm_b_hh, lin_w, lin_b, ebuf, (float*)d_out);
}